// Round 8
// baseline (325.825 us; speedup 1.0000x reference)
//
#include <hip/hip_runtime.h>

#define B_ 8
#define S_ 2048
#define M_ 256
#define D_ 512
#define P_ 512
#define H_ 8

#define SCALE 0.044194173824159216f  // 1/sqrt(512)

typedef __attribute__((ext_vector_type(8))) short bf16x8;
typedef __attribute__((ext_vector_type(4))) float f32x4;

static __device__ __forceinline__ float bf2f(short u) {
  union { float f; unsigned int i; } x;
  x.i = ((unsigned int)(unsigned short)u) << 16;
  return x.f;
}
static __device__ __forceinline__ short f2bf(float f) {
  union { float f; unsigned int i; } x;
  x.f = f;
  unsigned int r = (x.i + 0x7FFFu + ((x.i >> 16) & 1u)) >> 16;
  return (short)r;
}

// async global->LDS, 16B per lane; lds base must be wave-uniform
static __device__ __forceinline__ void gll16(const short* g, short* l) {
  __builtin_amdgcn_global_load_lds(
      (const __attribute__((address_space(1))) void*)g,
      (__attribute__((address_space(3))) void*)l, 16, 0, 0);
}

#define LGKM_WAIT() asm volatile("s_waitcnt lgkmcnt(0)" ::: "memory")
#define RAW_BAR() do { asm volatile("" ::: "memory"); __builtin_amdgcn_s_barrier(); asm volatile("" ::: "memory"); } while (0)

// ---------------------------------------------------------------------------
// fused fp32 -> bf16 cast (RNE) for input_seq and memory_cells
// ---------------------------------------------------------------------------
__global__ __launch_bounds__(256) void cast_both(
    const float* __restrict__ inA, short* __restrict__ outA, int n4A,
    const float* __restrict__ inM, short* __restrict__ outM)
{
  int idx = blockIdx.x * 256 + threadIdx.x;
  const float* in = inA;
  short* out = outA;
  if (idx >= n4A) { idx -= n4A; in = inM; out = outM; }
  float4 v = ((const float4*)in)[idx];
  short o0 = f2bf(v.x), o1 = f2bf(v.y), o2 = f2bf(v.z), o3 = f2bf(v.w);
  uint2 pk;
  pk.x = (unsigned int)(unsigned short)o0 | ((unsigned int)(unsigned short)o1 << 16);
  pk.y = (unsigned int)(unsigned short)o2 | ((unsigned int)(unsigned short)o3 << 16);
  ((uint2*)out)[idx] = pk;
}

// ---------------------------------------------------------------------------
// merged weight transpose+cast for the 512x512 weights
// ---------------------------------------------------------------------------
__global__ __launch_bounds__(256) void wtrans_all(
    const float* __restrict__ Wk, const float* __restrict__ Wv,
    const float* __restrict__ Wq,
    short* __restrict__ WkT, short* __restrict__ WvT, short* __restrict__ WqT)
{
  __shared__ float tile[32][33];
  const int t = threadIdx.x, tx = t & 31, ty = t >> 5;
  const int z = blockIdx.z;
  const float* inp;
  short* outp;
  if (z == 0)      { inp = Wk; outp = WkT; }
  else if (z == 1) { inp = Wv; outp = WvT; }
  else             { inp = Wq + (size_t)(z - 2) * 512 * 512;
                     outp = WqT + (size_t)(z - 2) * 512 * 512; }
  const int n0 = blockIdx.x * 32, k0 = blockIdx.y * 32;
#pragma unroll
  for (int i = 0; i < 4; ++i)
    tile[ty + 8 * i][tx] = inp[(size_t)(k0 + ty + 8 * i) * 512 + n0 + tx];
  __syncthreads();
#pragma unroll
  for (int i = 0; i < 4; ++i)
    outp[(size_t)(n0 + ty + 8 * i) * 512 + k0 + tx] = f2bf(tile[tx][ty + 8 * i]);
}

// ---------------------------------------------------------------------------
// Wo transpose+cast: [4096 k][512 n] fp32 -> [512 n][4096 k] bf16
// ---------------------------------------------------------------------------
__global__ __launch_bounds__(256) void wtrans_wo(
    const float* __restrict__ in, short* __restrict__ out)
{
  __shared__ float tile[32][33];
  const int t = threadIdx.x, tx = t & 31, ty = t >> 5;
  const int n0 = blockIdx.x * 32, k0 = blockIdx.y * 32;
#pragma unroll
  for (int i = 0; i < 4; ++i)
    tile[ty + 8 * i][tx] = in[(size_t)(k0 + ty + 8 * i) * 512 + n0 + tx];
  __syncthreads();
#pragma unroll
  for (int i = 0; i < 4; ++i)
    out[(size_t)(n0 + ty + 8 * i) * 4096 + k0 + tx] = f2bf(tile[tx][ty + 8 * i]);
}

// ---------------------------------------------------------------------------
// 128x128 MFMA GEMM, BK=32, 2-barrier single-buffer K-loop. Used for
// MODE 1 (q projection) and MODE 5 (Wo split-K).
// ---------------------------------------------------------------------------
template<int MODE, int K, int N, int LDA, int LDB>
__global__ __launch_bounds__(256, 3) void gemm128(
    const short* __restrict__ Abase, const short* __restrict__ Bbase,
    const float* __restrict__ bias, void* __restrict__ Cv,
    const size_t aZ, const size_t bZ, const size_t cZ,
    float* __restrict__ Ls,
    const float* __restrict__ eselfp, const short* __restrict__ mvbp)
{
  __shared__ short As[4096];
  __shared__ short Bs[4096];
  const int t = threadIdx.x;
  const int w = t >> 6, lane = t & 63, qd = lane >> 4, ln = lane & 15;
  const int wm = (w & 1) * 64, wn = (w >> 1) * 64;

  const int n0 = blockIdx.x * 128;
  const int m0 = blockIdx.y * 128;
  const int z = blockIdx.z;
  const int bsel = z;

  const short* A  = Abase + (size_t)z * aZ;
  const short* Bp = Bbase + (size_t)bsel * bZ;

  const int rr = t >> 2, g0 = t & 3;
  const int gs0 = g0 ^ ((rr >> 1) & 3);
  const int gs1 = g0 ^ (((rr + 64) >> 1) & 3);
  const short* ga0 = A + (size_t)(m0 + rr) * LDA + gs0 * 8;
  const short* ga1 = A + (size_t)(m0 + rr + 64) * LDA + gs1 * 8;
  const short* gb0 = Bp + (size_t)(n0 + rr) * LDB + gs0 * 8;
  const short* gb1 = Bp + (size_t)(n0 + rr + 64) * LDB + gs1 * 8;

  int aoff[4], boff[4];
#pragma unroll
  for (int mt = 0; mt < 4; ++mt) {
    int r = wm + mt * 16 + ln;
    aoff[mt] = r * 32 + (qd ^ ((r >> 1) & 3)) * 8;
  }
#pragma unroll
  for (int nt = 0; nt < 4; ++nt) {
    int r = wn + nt * 16 + ln;
    boff[nt] = r * 32 + (qd ^ ((r >> 1) & 3)) * 8;
  }

  f32x4 acc[4][4];
#pragma unroll
  for (int mt = 0; mt < 4; ++mt)
#pragma unroll
    for (int nt = 0; nt < 4; ++nt) acc[mt][nt] = (f32x4){0.f, 0.f, 0.f, 0.f};

  for (int kc = 0; kc < K; kc += 32) {
    __syncthreads();
    gll16(ga0 + kc, &As[w * 512]);
    gll16(ga1 + kc, &As[2048 + w * 512]);
    gll16(gb0 + kc, &Bs[w * 512]);
    gll16(gb1 + kc, &Bs[2048 + w * 512]);
    __syncthreads();

    bf16x8 af[4], bfr[4];
#pragma unroll
    for (int mt = 0; mt < 4; ++mt) af[mt] = *(const bf16x8*)&As[aoff[mt]];
#pragma unroll
    for (int nt = 0; nt < 4; ++nt) bfr[nt] = *(const bf16x8*)&Bs[boff[nt]];
#pragma unroll
    for (int mt = 0; mt < 4; ++mt)
#pragma unroll
      for (int nt = 0; nt < 4; ++nt)
        acc[mt][nt] = __builtin_amdgcn_mfma_f32_16x16x32_bf16(af[mt], bfr[nt], acc[mt][nt], 0, 0, 0);
  }

  if constexpr (MODE == 5) {
#pragma unroll
    for (int nt = 0; nt < 4; ++nt) {
      const int col = n0 + wn + nt * 16 + ln;
#pragma unroll
      for (int mt = 0; mt < 4; ++mt)
#pragma unroll
        for (int r = 0; r < 4; ++r) {
          const int row = m0 + wm + mt * 16 + qd * 4 + r;
          ((float*)Cv)[(size_t)z * cZ + (size_t)row * N + col] = acc[mt][nt][r];
        }
    }
  } else {  // MODE 1
#pragma unroll
    for (int nt = 0; nt < 4; ++nt) {
      const int col = n0 + wn + nt * 16 + ln;
      const float bc = bias[512 * z + col];
#pragma unroll
      for (int mt = 0; mt < 4; ++mt)
#pragma unroll
        for (int r = 0; r < 4; ++r) {
          const int row = m0 + wm + mt * 16 + qd * 4 + r;
          const int bidx = row >> 8, ml = row & 255;
          ((short*)Cv)[((size_t)(bidx * H_ + z) * M_ + ml) * N + col] = f2bf(acc[mt][nt][r] + bc);
        }
    }
  }
}

// ---------------------------------------------------------------------------
// gemm7: reg-double-buffered ring-4 pipeline. 128x128 tile, BK=32, 256 thr
// (4 waves 2Mx2N, wave 64x64, acc[4][4]). LDS 64 KiB: A ring-4 x 8 KB @0,
// B ring-4 x 8 KB @16384(shorts). 2 blocks/CU.
//
// WHY (rounds 0-6): every structure so far (4-phase, 1-barrier, ring-3,
// 2x/3x occupancy) pinned MfmaUtil at 20-23% -- the per-wave chain
// {ds_read -> lgkm wait -> MFMA -> drain -> barrier} serializes LDS-read
// latency IN FRONT of the MFMA window (~78cy useful of ~1000cy period).
// Fix = read tile t+1's fragments into an ALTERNATE register set while
// MFMAing tile t (m201's missing piece at register level):
//   iter kt: [a] 8 ds_reads frags(kt+1) -> nxt set
//            [b] stage(kt+3) -> buf[(kt+3)&3] (4 gll16)
//            sched_barrier(0)   // pin issue order: reads/stage above MFMA
//            [c] 16 MFMA on cur set (no lgkm dep -> compiler counted lgkm)
//            [d] lgkmcnt(0); vmcnt(4)  // drains stage(kt+2), age ~1 iter;
//                                      // stage(kt+3) stays in flight
//            [e] barrier; swap sets (static 2x unroll, no dyn indexing)
// Hazards (all >= 1 barrier + explicit drain apart):
//  - reads(kt.a) of tile kt+1: staged (kt-2).b, vmcnt-drained by every wave
//    at (kt-1).d BEFORE its barrier arrival -> visible post-barrier. OK
//  - gll16 stage(kt+3) overwrites buf[(kt-1)&3]: last reads (kt-2).a were
//    lgkm(0)-drained (kt-2).d + 2 barriers before kt.b. OK
//  - prologue: stage 0,1,2; vmcnt(4) (tiles 0,1 drained; 2 in flight).
//  - vmcnt(N) with <N outstanding = no-op; tails use vmcnt(0). No hang.
// Swizzle (4-chunk rows, r4/r6-verified 0 conflicts): chunk'=c^((row>>1)&3)
// via pre-swizzled global source (rule 21); frag chunk qd^((ln>>1)&3).
// K-accumulation order identical to r6's PASSING kernels (bit-identical).
// MODE 2 = QK epilogue (exp + rowsum atomics + repack + 16B stores),
// MODE 3 = PV epilogue (normalize + eself*mv + repack + concat stores).
// [Round 7 bench was an infra failure (container, no compile error); this
//  is the same kernel resubmitted for measurement.]
// ---------------------------------------------------------------------------
template<int NKT, int MODE, int LDA, int LDB>
__global__ __launch_bounds__(256, 2) void gemm7(
    const short* __restrict__ Abase, const short* __restrict__ Bbase,
    short* __restrict__ Cb, float* __restrict__ Ls,
    const float* __restrict__ eselfp, const short* __restrict__ mvbp,
    const size_t aZ, const size_t bZ)
{
  __shared__ short lds[32768];   // 64 KiB
  const int t = threadIdx.x;
  const int w = t >> 6, lane = t & 63, qd = lane >> 4, ln = lane & 15;
  const int wrp = w & 1, wcp = w >> 1;            // 2M x 2N
  const int b = blockIdx.x;                       // XCD pin: flat id % 8 == b
  const int n0 = blockIdx.y * 128, m0 = blockIdx.z * 128;

  const short* A  = Abase + (size_t)b * aZ + (size_t)m0 * LDA;
  const short* Bp = Bbase + (size_t)b * bZ + (size_t)n0 * LDB;

  // staging source: slot s=t (x2) <- global(row=s>>2, chunk=(s&3)^((row>>1)&3))
  const int srow = t >> 2;
  const int scol = ((t & 3) ^ ((srow >> 1) & 3)) * 8;
  const short* gsA = A  + (size_t)srow * LDA + scol;
  const short* gsB = Bp + (size_t)srow * LDB + scol;

  auto stageT = [&](int kt) {     // stage tile kt into ring slot kt&3
    short* la = &lds[(kt & 3) * 4096];
    short* lb = &lds[16384 + (kt & 3) * 4096];
    const short* ga = gsA + (size_t)kt * 32;
    const short* gb = gsB + (size_t)kt * 32;
    gll16(ga, la + w * 512);
    gll16(ga + (size_t)64 * LDA, la + 2048 + w * 512);
    gll16(gb, lb + w * 512);
    gll16(gb + (size_t)64 * LDB, lb + 2048 + w * 512);
  };

  // fragment offsets: row stride 32 shorts, chunk' = qd ^ ((ln>>1)&3)
  const int fq = (qd ^ ((ln >> 1) & 3)) * 8;
  int aoff[4], boff[4];
#pragma unroll
  for (int mt = 0; mt < 4; ++mt) aoff[mt] = (wrp * 64 + mt * 16 + ln) * 32 + fq;
#pragma unroll
  for (int nt = 0; nt < 4; ++nt) boff[nt] = (wcp * 64 + nt * 16 + ln) * 32 + fq;

  f32x4 acc[4][4];
#pragma unroll
  for (int i = 0; i < 4; ++i)
#pragma unroll
    for (int j = 0; j < 4; ++j) acc[i][j] = (f32x4){0.f, 0.f, 0.f, 0.f};

  bf16x8 aX[4], bX[4], aY[4], bY[4];

  // ---- prologue: stage tiles 0,1,2; drain 0,1; read frags(0) -> X
  stageT(0); stageT(1); stageT(2);
  asm volatile("s_waitcnt vmcnt(4)" ::: "memory");
  __builtin_amdgcn_s_barrier();
  {
    const short* Ah = &lds[0];
    const short* Bh = &lds[16384];
#pragma unroll
    for (int nt = 0; nt < 4; ++nt) bX[nt] = *(const bf16x8*)&Bh[boff[nt]];
#pragma unroll
    for (int mt = 0; mt < 4; ++mt) aX[mt] = *(const bf16x8*)&Ah[aoff[mt]];
  }

  auto iter = [&](int kt, bf16x8 (&ca)[4], bf16x8 (&cb)[4],
                  bf16x8 (&na)[4], bf16x8 (&nb)[4]) {
    if (kt + 1 < NKT) {
      const short* Ah = &lds[((kt + 1) & 3) * 4096];
      const short* Bh = &lds[16384 + ((kt + 1) & 3) * 4096];
#pragma unroll
      for (int nt = 0; nt < 4; ++nt) nb[nt] = *(const bf16x8*)&Bh[boff[nt]];
#pragma unroll
      for (int mt = 0; mt < 4; ++mt) na[mt] = *(const bf16x8*)&Ah[aoff[mt]];
    }
    if (kt + 3 < NKT) stageT(kt + 3);
    __builtin_amdgcn_sched_barrier(0);
    __builtin_amdgcn_s_setprio(1);
#pragma unroll
    for (int mt = 0; mt < 4; ++mt)
#pragma unroll
      for (int nt = 0; nt < 4; ++nt)
        acc[mt][nt] = __builtin_amdgcn_mfma_f32_16x16x32_bf16(ca[mt], cb[nt], acc[mt][nt], 0, 0, 0);
    __builtin_amdgcn_s_setprio(0);
    asm volatile("s_waitcnt lgkmcnt(0)" ::: "memory");
    if (kt + 3 < NKT) { asm volatile("s_waitcnt vmcnt(4)" ::: "memory"); }
    else              { asm volatile("s_waitcnt vmcnt(0)" ::: "memory"); }
    RAW_BAR();
  };

#pragma unroll 1
  for (int kt = 0; kt < NKT; kt += 2) {
    iter(kt,     aX, bX, aY, bY);
    iter(kt + 1, aY, bY, aX, bX);
  }

  // ---- epilogues ----
  if constexpr (MODE == 2) {
#pragma unroll
    for (int i = 0; i < 4; ++i)
#pragma unroll
      for (int j = 0; j < 4; ++j)
#pragma unroll
        for (int r = 0; r < 4; ++r)
          acc[i][j][r] = __expf(acc[i][j][r] * SCALE);
#pragma unroll
    for (int i = 0; i < 4; ++i)
#pragma unroll
      for (int r = 0; r < 4; ++r) {
        float rs = acc[i][0][r] + acc[i][1][r] + acc[i][2][r] + acc[i][3][r];
        rs += __shfl_xor(rs, 1);
        rs += __shfl_xor(rs, 2);
        rs += __shfl_xor(rs, 4);
        rs += __shfl_xor(rs, 8);
        if (ln == 0) {
          const int row = m0 + wrp * 64 + i * 16 + qd * 4 + r;
          atomicAdd(&Ls[(size_t)b * 2048 + row], rs);
        }
      }
#pragma unroll
    for (int i = 0; i < 4; ++i)
#pragma unroll
      for (int j = 0; j < 4; ++j)
#pragma unroll
        for (int r = 0; r < 4; ++r) {
          const int row = wrp * 64 + i * 16 + qd * 4 + r;
          const int col = wcp * 64 + j * 16 + ln;
          lds[row * 128 + (col ^ ((row & 7) << 3))] = f2bf(acc[i][j][r]);
        }
    LGKM_WAIT();
    RAW_BAR();
    short* Co = Cb + (size_t)b * 2048 * 2048;
#pragma unroll
    for (int it = 0; it < 8; ++it) {
      const int flat = it * 256 + t;
      const int row = flat >> 4, c = flat & 15;
      bf16x8 v = *(const bf16x8*)&lds[row * 128 + ((c ^ (row & 7)) * 8)];
      *(bf16x8*)(Co + (size_t)(m0 + row) * 2048 + n0 + c * 8) = v;
    }
  } else {  // MODE 3
#pragma unroll
    for (int mt = 0; mt < 4; ++mt)
#pragma unroll
      for (int r = 0; r < 4; ++r) {
        const int rl = wrp * 64 + mt * 16 + qd * 4 + r;   // local row 0..127
        const int R = m0 + rl;                            // h*256+m row
        const float es  = eselfp[(size_t)b * 2048 + R];
        const float inv = 1.f / (es + Ls[(size_t)b * 2048 + R]);
        const short* mvr = mvbp + ((size_t)(b * 256 + (R & 255))) * 512;
#pragma unroll
        for (int j = 0; j < 4; ++j) {
          const int lcol = wcp * 64 + j * 16 + ln;
          const float v = (acc[mt][j][r] + es * bf2f(mvr[n0 + lcol])) * inv;
          lds[rl * 128 + (lcol ^ ((rl & 7) << 3))] = f2bf(v);
        }
      }
    LGKM_WAIT();
    RAW_BAR();
#pragma unroll
    for (int it = 0; it < 8; ++it) {
      const int flat = it * 256 + t;
      const int row = flat >> 4, c = flat & 15;
      const int R = m0 + row;
      bf16x8 v = *(const bf16x8*)&lds[row * 128 + ((c ^ (row & 7)) * 8)];
      *(bf16x8*)(Cb + ((size_t)(b * 256 + (R & 255))) * 4096
                 + (size_t)(R >> 8) * 512 + n0 + c * 8) = v;
    }
  }
}

// ---------------------------------------------------------------------------
// merged K/V projection, BK=32, 2-barrier single-buffer (16 KB LDS).
// ---------------------------------------------------------------------------
template<bool TRANSV>
__global__ __launch_bounds__(256, 3) void proj_kv(
    const short* __restrict__ A,
    const short* __restrict__ WkT, const short* __restrict__ WvT,
    const float* __restrict__ bk, const float* __restrict__ bv,
    short* __restrict__ Ck, short* __restrict__ Cvv)
{
  __shared__ short Sh[8192];
  short* As  = Sh;
  short* Bks = Sh + 4096;
  short* Bvs = Sh + 6144;
  const int t = threadIdx.x;
  const int w = t >> 6, lane = t & 63, qd = lane >> 4, ln = lane & 15;
  const int n0 = blockIdx.x * 64, m0 = blockIdx.y * 128;
  const int wm = (w & 1) * 64, wn2 = (w >> 1) * 32;

  const int rr = t >> 2, g0 = t & 3;
  const int gs0 = g0 ^ ((rr >> 1) & 3);
  const int gs1 = g0 ^ (((rr + 64) >> 1) & 3);
  const short* ga0 = A + (size_t)(m0 + rr) * 512 + gs0 * 8;
  const short* ga1 = A + (size_t)(m0 + rr + 64) * 512 + gs1 * 8;
  const short* gbk = WkT + (size_t)(n0 + rr) * 512 + gs0 * 8;
  const short* gbv = WvT + (size_t)(n0 + rr) * 512 + gs0 * 8;

  int aoff[4], boff[2];
#pragma unroll
  for (int mt = 0; mt < 4; ++mt) {
    int r = wm + mt * 16 + ln;
    aoff[mt] = r * 32 + (qd ^ ((r >> 1) & 3)) * 8;
  }
#pragma unroll
  for (int nt = 0; nt < 2; ++nt) {
    int r = wn2 + nt * 16 + ln;
    boff[nt] = r * 32 + (qd ^ ((r >> 1) & 3)) * 8;
  }

  f32x4 accK[4][2], accV[4][2];
#pragma unroll
  for (int mt = 0; mt < 4; ++mt)
#pragma unroll
    for (int nt = 0; nt < 2; ++nt) {
      accK[mt][nt] = (f32x4){0.f, 0.f, 0.f, 0.f};
      accV[mt][nt] = (f32x4){0.f, 0.f, 0.f, 0.f};
    }

  for (int kc = 0; kc < 512; kc += 32) {
    __syncthreads();
    gll16(ga0 + kc, &As[w * 512]);
    gll16(ga1 + kc, &As[2048 + w * 512]);
    gll16(gbk + kc, &Bks[w * 512]);
    gll16(gbv + kc, &Bvs[w * 512]);
    __syncthreads();

    bf16x8 af[4], bkf[2], bvf[2];
#pragma unroll
    for (int mt = 0; mt < 4; ++mt) af[mt] = *(const bf16x8*)&As[aoff[mt]];
#pragma unroll
    for (int nt = 0; nt < 2; ++nt) {
      bkf[nt] = *(const bf16x8*)&Bks[boff[nt]];
      bvf[nt] = *(const bf16x8*)&Bvs[boff[nt]];
    }
#pragma unroll
    for (int mt = 0; mt < 4; ++mt)
#pragma unroll
      for (int nt = 0; nt < 2; ++nt) {
        accK[mt][nt] = __builtin_amdgcn_mfma_f32_16x16x32_bf16(af[mt], bkf[nt], accK[mt][nt], 0, 0, 0);
        accV[mt][nt] = __builtin_amdgcn_mfma_f32_16x16x32_bf16(af[mt], bvf[nt], accV[mt][nt], 0, 0, 0);
      }
  }

#pragma unroll
  for (int nt = 0; nt < 2; ++nt) {
    const int col = n0 + wn2 + nt * 16 + ln;
    const float bc = bk[col];
#pragma unroll
    for (int mt = 0; mt < 4; ++mt)
#pragma unroll
      for (int r = 0; r < 4; ++r) {
        const int row = m0 + wm + mt * 16 + qd * 4 + r;
        Ck[(size_t)row * 512 + col] = f2bf(accK[mt][nt][r] + bc);
      }
  }

  if constexpr (!TRANSV) {
#pragma unroll
    for (int nt = 0; nt < 2; ++nt) {
      const int col = n0 + wn2 + nt * 16 + ln;
      const float bc = bv[col];
#pragma unroll
      for (int mt = 0; mt < 4; ++mt)
#pragma unroll
        for (int r = 0; r < 4; ++r) {
          const int row = m0 + wm + mt * 16 + qd * 4 + r;
          Cvv[(size_t)row * 512 + col] = f2bf(accV[mt][nt][r] + bc);
        }
    }
  } else {
    __syncthreads();
    short* ep = &Sh[w * 1280];
    const int lr = lane >> 1, lc16 = (lane & 1) * 16;
#pragma unroll
    for (int pass = 0; pass < 2; ++pass) {
#pragma unroll
      for (int mh = 0; mh < 2; ++mh) {
        const int mt = pass * 2 + mh;
#pragma unroll
        for (int nt = 0; nt < 2; ++nt) {
          const float bc = bv[n0 + wn2 + nt * 16 + ln];
#pragma unroll
          for (int r = 0; r < 4; ++r)
            ep[(nt * 16 + ln) * 40 + mh * 16 + qd * 4 + r] = f2bf(accV[mt][nt][r] + bc);
        }
      }
      LGKM_WAIT();
      const int srow0 = m0 + wm + pass * 32;
      const int bidx = srow0 >> 11;
      const int sloc = (srow0 & 2047) + lc16;
      const int pcol = n0 + wn2 + lr;
      short* outp = Cvv + (size_t)bidx * P_ * S_ + (size_t)pcol * S_ + sloc;
      *(bf16x8*)outp = *(const bf16x8*)&ep[lr * 40 + lc16];
      *(bf16x8*)(outp + 8) = *(const bf16x8*)&ep[lr * 40 + lc16 + 8];
      LGKM_WAIT();
    }
  }
}

// ---------------------------------------------------------------------------
// split-K reduce for Wo: out = sum_z partial[z] + bo[col], fp32
// ---------------------------------------------------------------------------
__global__ __launch_bounds__(256) void reduce_wo(
    const float* __restrict__ partial, const float* __restrict__ bo,
    float* __restrict__ out)
{
  const int idx4 = blockIdx.x * 256 + threadIdx.x;
  float4 s = ((const float4*)bo)[idx4 & 127];
#pragma unroll
  for (int zz = 0; zz < 4; ++zz) {
    float4 p = ((const float4*)partial)[(size_t)zz * 262144 + idx4];
    s.x += p.x; s.y += p.y; s.z += p.z; s.w += p.w;
  }
  ((float4*)out)[idx4] = s;
}

// ---------------------------------------------------------------------------
// self-score + Ls zeroing
// ---------------------------------------------------------------------------
__global__ __launch_bounds__(256) void selfscore(
    const short* __restrict__ qb, const short* __restrict__ mkb,
    float* __restrict__ eself, float* __restrict__ Ls)
{
  const int z = blockIdx.x, t = threadIdx.x;
  const short* qr = qb + ((size_t)z * M_ + t) * P_;
  const short* mr = mkb + ((size_t)(z >> 3) * M_ + t) * P_;
  float s = 0.f;
#pragma unroll 8
  for (int c = 0; c < P_; c += 8) {
    bf16x8 qv = *(const bf16x8*)(qr + c);
    bf16x8 mv = *(const bf16x8*)(mr + c);
#pragma unroll
    for (int j = 0; j < 8; ++j) s += bf2f(qv[j]) * bf2f(mv[j]);
  }
  eself[(size_t)z * M_ + t] = __expf(s * SCALE);
  Ls[(size_t)z * M_ + t] = 0.f;
}

// ---------------------------------------------------------------------------
extern "C" void kernel_launch(void* const* d_in, const int* in_sizes, int n_in,
                              void* d_out, int out_size, void* d_ws, size_t ws_size,
                              hipStream_t stream) {
  const float* input_seq = (const float*)d_in[0];
  const float* memcells  = (const float*)d_in[1];
  const float* Wk = (const float*)d_in[2];
  const float* bk = (const float*)d_in[3];
  const float* Wv = (const float*)d_in[4];
  const float* bv = (const float*)d_in[5];
  const float* Wq = (const float*)d_in[6];
  const float* bq = (const float*)d_in[7];
  const float* Wo = (const float*)d_in[8];
  const float* bo = (const float*)d_in[9];
  float* out = (float*)d_out;

  short* ws = (short*)d_ws;
  size_t o = 0;
  short* valb = ws + o; o += (size_t)B_ * M_ * H_ * P_;      // 8388608
  short* WoT  = ws + o; o += (size_t)(H_ * P_) * P_;          // 2097152
  short* mvb  = ws + o; o += (size_t)B_ * M_ * P_;            // 1048576
  short* mkb  = ws + o; o += (size_t)B_ * M_ * P_;            // 1048576
  short* qb   = ws + o; o += (size_t)B_ * H_ * M_ * P_;       // 8388608
  short* ivT  = ws + o; o += (size_t)B_ * P_ * S_;            // 8388608
  short* ikb  = ws + o; o += (size_t)B_ * S_ * P_;            // 8388608
  float* partial = (float*)(ws + o); o += (size_t)B_ * H_ * M_ * P_;  // 16 MB
  float* eself = (float*)(ws + o); o += 2 * (size_t)B_ * H_ * M_;
  float* Ls    = (float*)(ws + o); o += 2 * (size_t)B_ * H_ * M_;
  short* region2 = ws + o;                                    // Eb region (64 MB)
  short* Ab  = region2;
  short* Mb  = Ab + (size_t)B_ * S_ * D_;
  short* WkT = Mb + (size_t)B_ * M_ * D_;
  short* WvT = WkT + (size_t)D_ * P_;
  short* WqT = WvT + (size_t)D_ * P_;
  short* Eb  = region2;   // overlaps the above (all dead before E is written)

  dim3 blk(256);

  const int n4A = B_ * S_ * D_ / 4;
  const int n4M = B_ * M_ * D_ / 4;
  cast_both<<<dim3((n4A + n4M) / 256), blk, 0, stream>>>(input_seq, Ab, n4A, memcells, Mb);
  wtrans_all<<<dim3(16, 16, 10), blk, 0, stream>>>(Wk, Wv, Wq, WkT, WvT, WqT);
  wtrans_wo<<<dim3(16, 128), blk, 0, stream>>>(Wo, WoT);

  proj_kv<true><<<dim3(8, 128), blk, 0, stream>>>(Ab, WkT, WvT, bk, bv, ikb, ivT);
  proj_kv<false><<<dim3(8, 16), blk, 0, stream>>>(Mb, WkT, WvT, bk, bv, mkb, mvb);

  // q projection: MODE 1, z = h
  gemm128<1, 512, 512, 512, 512><<<dim3(4, 16, 8), blk, 0, stream>>>(
      Mb, WqT, bq, qb, 0, (size_t)D_ * P_, 0, nullptr, nullptr, nullptr);

  // eself + zero Ls (before QK's atomics)
  selfscore<<<dim3(64), blk, 0, stream>>>(qb, mkb, eself, Ls);

  // E = exp(scale * q @ ik^T) + fused row-sum; per-batch 2048x2048, K=512
  // reg-dbuf ring-4 pipeline; 2048 blocks, 64 KiB LDS -> 2 blocks/CU
  gemm7<16, 2, 512, 512><<<dim3(8, 16, 16), blk, 0, stream>>>(
      qb, ikb, Eb, Ls, nullptr, nullptr,
      (size_t)2048 * 512, (size_t)2048 * 512);

  // val = normalize(E @ iv + eself*mv), concat layout; per-batch 2048x512,
  // K=2048; reg-dbuf ring-4; 512 blocks -> 2/CU
  gemm7<64, 3, 2048, 2048><<<dim3(8, 4, 16), blk, 0, stream>>>(
      Eb, ivT, valb, Ls, eself, mvb,
      (size_t)2048 * 2048, (size_t)512 * 2048);

  // Wo: split-K=4 partials, then reduce+bias
  gemm128<5, 1024, 512, 4096, 4096><<<dim3(4, 16, 4), blk, 0, stream>>>(
      valb, WoT, nullptr, partial, 1024, 1024,
      (size_t)2048 * 512, nullptr, nullptr, nullptr);
  reduce_wo<<<dim3(1024), blk, 0, stream>>>(partial, bo, out);
}

// Round 9
// 302.980 us; speedup vs baseline: 1.0754x; 1.0754x over previous
//
#include <hip/hip_runtime.h>

#define B_ 8
#define S_ 2048
#define M_ 256
#define D_ 512
#define P_ 512
#define H_ 8

#define SCALE 0.044194173824159216f  // 1/sqrt(512)

typedef __attribute__((ext_vector_type(8))) short bf16x8;
typedef __attribute__((ext_vector_type(4))) float f32x4;

static __device__ __forceinline__ float bf2f(short u) {
  union { float f; unsigned int i; } x;
  x.i = ((unsigned int)(unsigned short)u) << 16;
  return x.f;
}
static __device__ __forceinline__ short f2bf(float f) {
  union { float f; unsigned int i; } x;
  x.f = f;
  unsigned int r = (x.i + 0x7FFFu + ((x.i >> 16) & 1u)) >> 16;
  return (short)r;
}

// async global->LDS, 16B per lane; lds base must be wave-uniform
static __device__ __forceinline__ void gll16(const short* g, short* l) {
  __builtin_amdgcn_global_load_lds(
      (const __attribute__((address_space(1))) void*)g,
      (__attribute__((address_space(3))) void*)l, 16, 0, 0);
}

#define LGKM_WAIT() asm volatile("s_waitcnt lgkmcnt(0)" ::: "memory")
#define VMLG_WAIT() asm volatile("s_waitcnt vmcnt(0) lgkmcnt(0)" ::: "memory")
#define RAW_BAR() do { asm volatile("" ::: "memory"); __builtin_amdgcn_s_barrier(); asm volatile("" ::: "memory"); } while (0)

// ---------------------------------------------------------------------------
// fused fp32 -> bf16 cast (RNE) for input_seq and memory_cells
// ---------------------------------------------------------------------------
__global__ __launch_bounds__(256) void cast_both(
    const float* __restrict__ inA, short* __restrict__ outA, int n4A,
    const float* __restrict__ inM, short* __restrict__ outM)
{
  int idx = blockIdx.x * 256 + threadIdx.x;
  const float* in = inA;
  short* out = outA;
  if (idx >= n4A) { idx -= n4A; in = inM; out = outM; }
  float4 v = ((const float4*)in)[idx];
  short o0 = f2bf(v.x), o1 = f2bf(v.y), o2 = f2bf(v.z), o3 = f2bf(v.w);
  uint2 pk;
  pk.x = (unsigned int)(unsigned short)o0 | ((unsigned int)(unsigned short)o1 << 16);
  pk.y = (unsigned int)(unsigned short)o2 | ((unsigned int)(unsigned short)o3 << 16);
  ((uint2*)out)[idx] = pk;
}

// ---------------------------------------------------------------------------
// merged weight transpose+cast for the 512x512 weights
// ---------------------------------------------------------------------------
__global__ __launch_bounds__(256) void wtrans_all(
    const float* __restrict__ Wk, const float* __restrict__ Wv,
    const float* __restrict__ Wq,
    short* __restrict__ WkT, short* __restrict__ WvT, short* __restrict__ WqT)
{
  __shared__ float tile[32][33];
  const int t = threadIdx.x, tx = t & 31, ty = t >> 5;
  const int z = blockIdx.z;
  const float* inp;
  short* outp;
  if (z == 0)      { inp = Wk; outp = WkT; }
  else if (z == 1) { inp = Wv; outp = WvT; }
  else             { inp = Wq + (size_t)(z - 2) * 512 * 512;
                     outp = WqT + (size_t)(z - 2) * 512 * 512; }
  const int n0 = blockIdx.x * 32, k0 = blockIdx.y * 32;
#pragma unroll
  for (int i = 0; i < 4; ++i)
    tile[ty + 8 * i][tx] = inp[(size_t)(k0 + ty + 8 * i) * 512 + n0 + tx];
  __syncthreads();
#pragma unroll
  for (int i = 0; i < 4; ++i)
    outp[(size_t)(n0 + ty + 8 * i) * 512 + k0 + tx] = f2bf(tile[tx][ty + 8 * i]);
}

// ---------------------------------------------------------------------------
// Wo transpose+cast: [4096 k][512 n] fp32 -> [512 n][4096 k] bf16
// ---------------------------------------------------------------------------
__global__ __launch_bounds__(256) void wtrans_wo(
    const float* __restrict__ in, short* __restrict__ out)
{
  __shared__ float tile[32][33];
  const int t = threadIdx.x, tx = t & 31, ty = t >> 5;
  const int n0 = blockIdx.x * 32, k0 = blockIdx.y * 32;
#pragma unroll
  for (int i = 0; i < 4; ++i)
    tile[ty + 8 * i][tx] = in[(size_t)(k0 + ty + 8 * i) * 512 + n0 + tx];
  __syncthreads();
#pragma unroll
  for (int i = 0; i < 4; ++i)
    out[(size_t)(n0 + ty + 8 * i) * 4096 + k0 + tx] = f2bf(tile[tx][ty + 8 * i]);
}

// ---------------------------------------------------------------------------
// 128x128 MFMA GEMM, BK=32. UPGRADED to the r3-proven 1-barrier double-buffer
// loop (was 2-syncthreads single-buffer): read frags from buf p | stage
// kc+32 -> buf p^1 | 16 MFMA | vmcnt(0)+lgkm(0) | barrier. Staging now
// overlaps MFMA. LDS 32 KiB (2x8KB A + 2x8KB B), still 3 blocks/CU.
// Hazard: buf p^1 was fully read last iter; every wave lgkm(0)-drained those
// reads before the barrier that admitted this iter's stages (r3 calculus).
// Used for MODE 1 (q projection) and MODE 5 (Wo split-K).
// ---------------------------------------------------------------------------
template<int MODE, int K, int N, int LDA, int LDB>
__global__ __launch_bounds__(256, 3) void gemm128(
    const short* __restrict__ Abase, const short* __restrict__ Bbase,
    const float* __restrict__ bias, void* __restrict__ Cv,
    const size_t aZ, const size_t bZ, const size_t cZ,
    float* __restrict__ Ls,
    const float* __restrict__ eselfp, const short* __restrict__ mvbp)
{
  __shared__ short As[8192];   // 2 x 128x32
  __shared__ short Bs[8192];
  const int t = threadIdx.x;
  const int w = t >> 6, lane = t & 63, qd = lane >> 4, ln = lane & 15;
  const int wm = (w & 1) * 64, wn = (w >> 1) * 64;

  const int n0 = blockIdx.x * 128;
  const int m0 = blockIdx.y * 128;
  const int z = blockIdx.z;

  const short* A  = Abase + (size_t)z * aZ;
  const short* Bp = Bbase + (size_t)z * bZ;

  const int rr = t >> 2, g0 = t & 3;
  const int gs0 = g0 ^ ((rr >> 1) & 3);
  const int gs1 = g0 ^ (((rr + 64) >> 1) & 3);
  const short* ga0 = A + (size_t)(m0 + rr) * LDA + gs0 * 8;
  const short* ga1 = A + (size_t)(m0 + rr + 64) * LDA + gs1 * 8;
  const short* gb0 = Bp + (size_t)(n0 + rr) * LDB + gs0 * 8;
  const short* gb1 = Bp + (size_t)(n0 + rr + 64) * LDB + gs1 * 8;

  int aoff[4], boff[4];
#pragma unroll
  for (int mt = 0; mt < 4; ++mt) {
    int r = wm + mt * 16 + ln;
    aoff[mt] = r * 32 + (qd ^ ((r >> 1) & 3)) * 8;
  }
#pragma unroll
  for (int nt = 0; nt < 4; ++nt) {
    int r = wn + nt * 16 + ln;
    boff[nt] = r * 32 + (qd ^ ((r >> 1) & 3)) * 8;
  }

  f32x4 acc[4][4];
#pragma unroll
  for (int mt = 0; mt < 4; ++mt)
#pragma unroll
    for (int nt = 0; nt < 4; ++nt) acc[mt][nt] = (f32x4){0.f, 0.f, 0.f, 0.f};

  // prologue: stage tile0 -> buf0
  gll16(ga0, &As[w * 512]);
  gll16(ga1, &As[2048 + w * 512]);
  gll16(gb0, &Bs[w * 512]);
  gll16(gb1, &Bs[2048 + w * 512]);
  asm volatile("s_waitcnt vmcnt(0)" ::: "memory");
  __builtin_amdgcn_s_barrier();

#pragma unroll 1
  for (int kc = 0; kc < K; kc += 32) {
    const int p = (kc >> 5) & 1;
    short* Ap = &As[p * 4096];
    short* Bq = &Bs[p * 4096];

    bf16x8 af[4], bfr[4];
#pragma unroll
    for (int mt = 0; mt < 4; ++mt) af[mt] = *(const bf16x8*)&Ap[aoff[mt]];
#pragma unroll
    for (int nt = 0; nt < 4; ++nt) bfr[nt] = *(const bf16x8*)&Bq[boff[nt]];

    if (kc + 32 < K) {
      const int nb = (p ^ 1) * 4096;
      gll16(ga0 + kc + 32, &As[nb + w * 512]);
      gll16(ga1 + kc + 32, &As[nb + 2048 + w * 512]);
      gll16(gb0 + kc + 32, &Bs[nb + w * 512]);
      gll16(gb1 + kc + 32, &Bs[nb + 2048 + w * 512]);
    }

    __builtin_amdgcn_s_setprio(1);
#pragma unroll
    for (int mt = 0; mt < 4; ++mt)
#pragma unroll
      for (int nt = 0; nt < 4; ++nt)
        acc[mt][nt] = __builtin_amdgcn_mfma_f32_16x16x32_bf16(af[mt], bfr[nt], acc[mt][nt], 0, 0, 0);
    __builtin_amdgcn_s_setprio(0);

    VMLG_WAIT();
    RAW_BAR();
  }

  if constexpr (MODE == 5) {
#pragma unroll
    for (int nt = 0; nt < 4; ++nt) {
      const int col = n0 + wn + nt * 16 + ln;
#pragma unroll
      for (int mt = 0; mt < 4; ++mt)
#pragma unroll
        for (int r = 0; r < 4; ++r) {
          const int row = m0 + wm + mt * 16 + qd * 4 + r;
          ((float*)Cv)[(size_t)z * cZ + (size_t)row * N + col] = acc[mt][nt][r];
        }
    }
  } else {  // MODE 1
#pragma unroll
    for (int nt = 0; nt < 4; ++nt) {
      const int col = n0 + wn + nt * 16 + ln;
      const float bc = bias[512 * z + col];
#pragma unroll
      for (int mt = 0; mt < 4; ++mt)
#pragma unroll
        for (int r = 0; r < 4; ++r) {
          const int row = m0 + wm + mt * 16 + qd * 4 + r;
          const int bidx = row >> 8, ml = row & 255;
          ((short*)Cv)[((size_t)(bidx * H_ + z) * M_ + ml) * N + col] = f2bf(acc[mt][nt][r] + bc);
        }
    }
  }
}

// ---------------------------------------------------------------------------
// QK kernel (round-3 best-measured, 56.2 us / 612 TF): 256x256 tile, BK=64,
// 512 thr (8 waves 2Mx4N, wave 128x64). ONE barrier per K-tile; compiler
// emits counted lgkmcnt between reads and MFMA so kk1's reads are serviced
// under kk0's MFMA window. Swizzle: chunk c of row r at c^(r&7), staged via
// pre-swizzled global source (verified 0 conflicts).
// ---------------------------------------------------------------------------
template<int NKT>
__global__ __launch_bounds__(512, 2) void qk256(
    const short* __restrict__ Abase, const short* __restrict__ Bbase,
    short* __restrict__ Eb, float* __restrict__ Ls)
{
  __shared__ short lds[65536];   // A: 2buf x [2half][128][64] | B same at +32768
  const int t = threadIdx.x;
  const int w = t >> 6, lane = t & 63, qd = lane >> 4, ln = lane & 15;
  const int wr = w >> 2, wc = w & 3;
  const int b = blockIdx.x;                       // XCD pin: flat id % 8 == b
  const int n0 = blockIdx.y * 256, m0 = blockIdx.z * 256;

  const short* A  = Abase + (size_t)b * (2048 * 512) + (size_t)m0 * 512;
  const short* Bp = Bbase + (size_t)b * (2048 * 512) + (size_t)n0 * 512;

  const int s0 = w * 64 + lane, s1 = s0 + 512;
  const int sr0 = s0 >> 3, sc0 = ((s0 & 7) ^ (sr0 & 7)) * 8;
  const int sr1 = s1 >> 3, sc1 = ((s1 & 7) ^ (sr1 & 7)) * 8;
  auto stage = [&](const short* g, short* lbase) {
    gll16(g + (size_t)sr0 * 512 + sc0, lbase + w * 512);
    gll16(g + (size_t)sr1 * 512 + sc1, lbase + 4096 + w * 512);
  };

  const int cq0 = ((qd    ) ^ (ln & 7)) * 8;
  const int cq1 = ((4 + qd) ^ (ln & 7)) * 8;
  const int brow = (wc & 1) * 64;

  f32x4 acc[8][4];
#pragma unroll
  for (int i = 0; i < 8; ++i)
#pragma unroll
    for (int j = 0; j < 4; ++j) acc[i][j] = (f32x4){0.f, 0.f, 0.f, 0.f};

  // ---- prologue: stage tile0, drain, go
  stage(A,              &lds[0]);
  stage(A + 128 * 512,  &lds[8192]);
  stage(Bp,             &lds[32768]);
  stage(Bp + 128 * 512, &lds[32768 + 8192]);
  asm volatile("s_waitcnt vmcnt(0)" ::: "memory");
  __builtin_amdgcn_s_barrier();

#pragma unroll 1
  for (int kt = 0; kt < NKT; ++kt) {
    const int p = kt & 1;
    short* Ah = &lds[p * 16384 + wr * 8192];
    short* Bh = &lds[32768 + p * 16384 + (wc >> 1) * 8192];

    bf16x8 a0[8], b0[4];
#pragma unroll
    for (int j = 0; j < 4; ++j)
      b0[j] = *(const bf16x8*)&Bh[(brow + j * 16 + ln) * 64 + cq0];
#pragma unroll
    for (int mt = 0; mt < 8; ++mt)
      a0[mt] = *(const bf16x8*)&Ah[(mt * 16 + ln) * 64 + cq0];
    if (kt + 1 < NKT) {
      stage(A  + (size_t)(kt + 1) * 64,             &lds[(p ^ 1) * 16384]);
      stage(A  + 128 * 512 + (size_t)(kt + 1) * 64, &lds[(p ^ 1) * 16384 + 8192]);
      stage(Bp + (size_t)(kt + 1) * 64,             &lds[32768 + (p ^ 1) * 16384]);
      stage(Bp + 128 * 512 + (size_t)(kt + 1) * 64, &lds[32768 + (p ^ 1) * 16384 + 8192]);
    }
    __builtin_amdgcn_s_setprio(1);
#pragma unroll
    for (int mt = 0; mt < 8; ++mt)
#pragma unroll
      for (int j = 0; j < 4; ++j)
        acc[mt][j] = __builtin_amdgcn_mfma_f32_16x16x32_bf16(a0[mt], b0[j], acc[mt][j], 0, 0, 0);
    __builtin_amdgcn_s_setprio(0);

    bf16x8 a1[8], b1[4];
#pragma unroll
    for (int j = 0; j < 4; ++j)
      b1[j] = *(const bf16x8*)&Bh[(brow + j * 16 + ln) * 64 + cq1];
#pragma unroll
    for (int mt = 0; mt < 8; ++mt)
      a1[mt] = *(const bf16x8*)&Ah[(mt * 16 + ln) * 64 + cq1];
    __builtin_amdgcn_s_setprio(1);
#pragma unroll
    for (int mt = 0; mt < 8; ++mt)
#pragma unroll
      for (int j = 0; j < 4; ++j)
        acc[mt][j] = __builtin_amdgcn_mfma_f32_16x16x32_bf16(a1[mt], b1[j], acc[mt][j], 0, 0, 0);
    __builtin_amdgcn_s_setprio(0);

    VMLG_WAIT();
    RAW_BAR();
  }

  // ---- epilogue: exp, rowsum atomics, LDS repack, coalesced stores
#pragma unroll
  for (int i = 0; i < 8; ++i)
#pragma unroll
    for (int j = 0; j < 4; ++j)
#pragma unroll
      for (int r = 0; r < 4; ++r)
        acc[i][j][r] = __expf(acc[i][j][r] * SCALE);
#pragma unroll
  for (int i = 0; i < 8; ++i)
#pragma unroll
    for (int r = 0; r < 4; ++r) {
      float rs = acc[i][0][r] + acc[i][1][r] + acc[i][2][r] + acc[i][3][r];
      rs += __shfl_xor(rs, 1);
      rs += __shfl_xor(rs, 2);
      rs += __shfl_xor(rs, 4);
      rs += __shfl_xor(rs, 8);
      if (ln == 0) {
        const int row = m0 + wr * 128 + i * 16 + qd * 4 + r;
        atomicAdd(&Ls[(size_t)b * 2048 + row], rs);
      }
    }
#pragma unroll
  for (int i = 0; i < 8; ++i)
#pragma unroll
    for (int j = 0; j < 4; ++j)
#pragma unroll
      for (int r = 0; r < 4; ++r) {
        const int row = wr * 128 + i * 16 + qd * 4 + r;
        const int col = wc * 64 + j * 16 + ln;
        lds[row * 256 + (col ^ ((row & 7) << 3))] = f2bf(acc[i][j][r]);
      }
  LGKM_WAIT();
  RAW_BAR();
  short* Cb = Eb + (size_t)b * 2048 * 2048;
#pragma unroll
  for (int it = 0; it < 16; ++it) {
    const int flat = it * 512 + t;
    const int row = flat >> 5, c = flat & 31;
    bf16x8 v = *(const bf16x8*)&lds[row * 256 + ((c ^ (row & 7)) * 8)];
    *(bf16x8*)(Cb + (size_t)(m0 + row) * 2048 + n0 + c * 8) = v;
  }
}

// ---------------------------------------------------------------------------
// PV kernel (round-4 best-measured variant): 256x128 tile, BK=64, NKT=32,
// 512 thr, wave grid 4Mx2N (wave 64x64). RING-3 LDS (144 KiB), counted
// boundary vmcnt(6). One barrier/tile.
// ---------------------------------------------------------------------------
template<int NKT>
__global__ __launch_bounds__(512, 2) void pv128(
    const short* __restrict__ Abase, const short* __restrict__ Bbase,
    short* __restrict__ valb, const float* __restrict__ Ls,
    const float* __restrict__ eselfp, const short* __restrict__ mvbp)
{
  __shared__ short lds[73728];   // A ring 3x16384 @0, B ring 3x8192 @49152
  const int t = threadIdx.x;
  const int w = t >> 6, lane = t & 63, qd = lane >> 4, ln = lane & 15;
  const int wr = w >> 1, wc = w & 1;              // 4M x 2N
  const int b = blockIdx.x;                       // XCD pin
  const int n0 = blockIdx.y * 128;
  const int bz = blockIdx.z;                      // head tile: m0 = bz*256
  const int m0 = bz * 256;

  const short* A  = Abase + (size_t)b * (2048 * 2048) + (size_t)m0 * 2048;
  const short* Bp = Bbase + (size_t)b * (512 * 2048) + (size_t)n0 * 2048;

  const int s0 = w * 64 + lane, s1 = s0 + 512;
  const int sr0 = s0 >> 3, sc0 = ((s0 & 7) ^ (sr0 & 7)) * 8;
  const int sr1 = s1 >> 3, sc1 = ((s1 & 7) ^ (sr1 & 7)) * 8;
  auto stage = [&](const short* g, short* lbase) {   // 8192 shorts (128 rows)
    gll16(g + (size_t)sr0 * 2048 + sc0, lbase + w * 512);
    gll16(g + (size_t)sr1 * 2048 + sc1, lbase + 4096 + w * 512);
  };

  const int cq0 = ((qd    ) ^ (ln & 7)) * 8;
  const int cq1 = ((4 + qd) ^ (ln & 7)) * 8;

  short* Ar = &lds[0];     short* An = &lds[16384]; short* Aw = &lds[32768];
  short* Br = &lds[49152]; short* Bn = &lds[57344]; short* Bw = &lds[65536];

  f32x4 acc[4][4];
#pragma unroll
  for (int i = 0; i < 4; ++i)
#pragma unroll
    for (int j = 0; j < 4; ++j) acc[i][j] = (f32x4){0.f, 0.f, 0.f, 0.f};

  // ---- prologue: tile0 -> buf0, tile1 -> buf1; wait tile0 only
  stage(A,                   Ar);
  stage(A + 128 * 2048,      Ar + 8192);
  stage(Bp,                  Br);
  stage(A + 64,              An);
  stage(A + 128 * 2048 + 64, An + 8192);
  stage(Bp + 64,             Bn);
  asm volatile("s_waitcnt vmcnt(6)" ::: "memory");
  __builtin_amdgcn_s_barrier();

#pragma unroll 1
  for (int kt = 0; kt < NKT; ++kt) {
    short* Ah = Ar + (wr >> 1) * 8192 + (wr & 1) * 4096;   // wave's 64-row window
    short* Bh = Br;

    bf16x8 a0[4], b0[4];
#pragma unroll
    for (int j = 0; j < 4; ++j)
      b0[j] = *(const bf16x8*)&Bh[(wc * 64 + j * 16 + ln) * 64 + cq0];
#pragma unroll
    for (int mt = 0; mt < 4; ++mt)
      a0[mt] = *(const bf16x8*)&Ah[(mt * 16 + ln) * 64 + cq0];

    if (kt + 2 < NKT) {
      stage(A  + (size_t)(kt + 2) * 64,              Aw);
      stage(A  + 128 * 2048 + (size_t)(kt + 2) * 64, Aw + 8192);
      stage(Bp + (size_t)(kt + 2) * 64,              Bw);
    }

    __builtin_amdgcn_s_setprio(1);
#pragma unroll
    for (int mt = 0; mt < 4; ++mt)
#pragma unroll
      for (int j = 0; j < 4; ++j)
        acc[mt][j] = __builtin_amdgcn_mfma_f32_16x16x32_bf16(a0[mt], b0[j], acc[mt][j], 0, 0, 0);
    __builtin_amdgcn_s_setprio(0);

    bf16x8 a1[4], b1[4];
#pragma unroll
    for (int j = 0; j < 4; ++j)
      b1[j] = *(const bf16x8*)&Bh[(wc * 64 + j * 16 + ln) * 64 + cq1];
#pragma unroll
    for (int mt = 0; mt < 4; ++mt)
      a1[mt] = *(const bf16x8*)&Ah[(mt * 16 + ln) * 64 + cq1];
    __builtin_amdgcn_s_setprio(1);
#pragma unroll
    for (int mt = 0; mt < 4; ++mt)
#pragma unroll
      for (int j = 0; j < 4; ++j)
        acc[mt][j] = __builtin_amdgcn_mfma_f32_16x16x32_bf16(a1[mt], b1[j], acc[mt][j], 0, 0, 0);
    __builtin_amdgcn_s_setprio(0);

    if (kt + 2 < NKT) { asm volatile("s_waitcnt vmcnt(6) lgkmcnt(0)" ::: "memory"); }
    else              { asm volatile("s_waitcnt vmcnt(0) lgkmcnt(0)" ::: "memory"); }
    RAW_BAR();

    short* tA = Ar; Ar = An; An = Aw; Aw = tA;
    short* tB = Br; Br = Bn; Bn = Bw; Bw = tB;
  }

  // ---- epilogue: normalize + self-attn term, LDS repack, coalesced stores
#pragma unroll
  for (int mt = 0; mt < 4; ++mt)
#pragma unroll
    for (int r = 0; r < 4; ++r) {
      const int row = wr * 64 + mt * 16 + qd * 4 + r;   // local row, R = m0+row
      const float es  = eselfp[(size_t)b * 2048 + m0 + row];
      const float inv = 1.f / (es + Ls[(size_t)b * 2048 + m0 + row]);
      const short* mvr = mvbp + ((size_t)(b * 256 + row)) * 512;
#pragma unroll
      for (int j = 0; j < 4; ++j) {
        const int lcol = wc * 64 + j * 16 + ln;
        const float v = (acc[mt][j][r] + es * bf2f(mvr[n0 + lcol])) * inv;
        lds[row * 128 + (lcol ^ ((row & 7) << 3))] = f2bf(v);
      }
    }
  LGKM_WAIT();
  RAW_BAR();
#pragma unroll
  for (int it = 0; it < 8; ++it) {
    const int flat = it * 512 + t;
    const int row = flat >> 4, c = flat & 15;
    bf16x8 v = *(const bf16x8*)&lds[row * 128 + ((c ^ (row & 7)) * 8)];
    *(bf16x8*)(valb + ((size_t)(b * 256 + row)) * 4096 + (size_t)bz * 512 + n0 + c * 8) = v;
  }
}

// ---------------------------------------------------------------------------
// merged K/V projection. UPGRADED to 1-barrier double-buffer (r3 schedule):
// LDS 32 KiB = 2 x {A 4096, Bk 2048, Bv 2048} shorts. Staging overlaps MFMA.
// ---------------------------------------------------------------------------
template<bool TRANSV>
__global__ __launch_bounds__(256, 3) void proj_kv(
    const short* __restrict__ A,
    const short* __restrict__ WkT, const short* __restrict__ WvT,
    const float* __restrict__ bk, const float* __restrict__ bv,
    short* __restrict__ Ck, short* __restrict__ Cvv)
{
  __shared__ short Sh[16384];  // dbuf: base = p*8192; A@0, Bk@4096, Bv@6144
  const int t = threadIdx.x;
  const int w = t >> 6, lane = t & 63, qd = lane >> 4, ln = lane & 15;
  const int n0 = blockIdx.x * 64, m0 = blockIdx.y * 128;
  const int wm = (w & 1) * 64, wn2 = (w >> 1) * 32;

  const int rr = t >> 2, g0 = t & 3;
  const int gs0 = g0 ^ ((rr >> 1) & 3);
  const int gs1 = g0 ^ (((rr + 64) >> 1) & 3);
  const short* ga0 = A + (size_t)(m0 + rr) * 512 + gs0 * 8;
  const short* ga1 = A + (size_t)(m0 + rr + 64) * 512 + gs1 * 8;
  const short* gbk = WkT + (size_t)(n0 + rr) * 512 + gs0 * 8;
  const short* gbv = WvT + (size_t)(n0 + rr) * 512 + gs0 * 8;

  int aoff[4], boff[2];
#pragma unroll
  for (int mt = 0; mt < 4; ++mt) {
    int r = wm + mt * 16 + ln;
    aoff[mt] = r * 32 + (qd ^ ((r >> 1) & 3)) * 8;
  }
#pragma unroll
  for (int nt = 0; nt < 2; ++nt) {
    int r = wn2 + nt * 16 + ln;
    boff[nt] = r * 32 + (qd ^ ((r >> 1) & 3)) * 8;
  }

  f32x4 accK[4][2], accV[4][2];
#pragma unroll
  for (int mt = 0; mt < 4; ++mt)
#pragma unroll
    for (int nt = 0; nt < 2; ++nt) {
      accK[mt][nt] = (f32x4){0.f, 0.f, 0.f, 0.f};
      accV[mt][nt] = (f32x4){0.f, 0.f, 0.f, 0.f};
    }

  // prologue: stage tile0 -> buf0
  gll16(ga0, &Sh[w * 512]);
  gll16(ga1, &Sh[2048 + w * 512]);
  gll16(gbk, &Sh[4096 + w * 512]);
  gll16(gbv, &Sh[6144 + w * 512]);
  asm volatile("s_waitcnt vmcnt(0)" ::: "memory");
  __builtin_amdgcn_s_barrier();

#pragma unroll 1
  for (int kc = 0; kc < 512; kc += 32) {
    const int base = ((kc >> 5) & 1) * 8192;

    bf16x8 af[4], bkf[2], bvf[2];
#pragma unroll
    for (int mt = 0; mt < 4; ++mt) af[mt] = *(const bf16x8*)&Sh[base + aoff[mt]];
#pragma unroll
    for (int nt = 0; nt < 2; ++nt) {
      bkf[nt] = *(const bf16x8*)&Sh[base + 4096 + boff[nt]];
      bvf[nt] = *(const bf16x8*)&Sh[base + 6144 + boff[nt]];
    }

    if (kc + 32 < 512) {
      const int nb = base ^ 8192;
      gll16(ga0 + kc + 32, &Sh[nb + w * 512]);
      gll16(ga1 + kc + 32, &Sh[nb + 2048 + w * 512]);
      gll16(gbk + kc + 32, &Sh[nb + 4096 + w * 512]);
      gll16(gbv + kc + 32, &Sh[nb + 6144 + w * 512]);
    }

    __builtin_amdgcn_s_setprio(1);
#pragma unroll
    for (int mt = 0; mt < 4; ++mt)
#pragma unroll
      for (int nt = 0; nt < 2; ++nt) {
        accK[mt][nt] = __builtin_amdgcn_mfma_f32_16x16x32_bf16(af[mt], bkf[nt], accK[mt][nt], 0, 0, 0);
        accV[mt][nt] = __builtin_amdgcn_mfma_f32_16x16x32_bf16(af[mt], bvf[nt], accV[mt][nt], 0, 0, 0);
      }
    __builtin_amdgcn_s_setprio(0);

    VMLG_WAIT();
    RAW_BAR();
  }

  // ---- K epilogue: direct scattered stores
#pragma unroll
  for (int nt = 0; nt < 2; ++nt) {
    const int col = n0 + wn2 + nt * 16 + ln;
    const float bc = bk[col];
#pragma unroll
    for (int mt = 0; mt < 4; ++mt)
#pragma unroll
      for (int r = 0; r < 4; ++r) {
        const int row = m0 + wm + mt * 16 + qd * 4 + r;
        Ck[(size_t)row * 512 + col] = f2bf(accK[mt][nt][r] + bc);
      }
  }

  // ---- V epilogue
  if constexpr (!TRANSV) {
#pragma unroll
    for (int nt = 0; nt < 2; ++nt) {
      const int col = n0 + wn2 + nt * 16 + ln;
      const float bc = bv[col];
#pragma unroll
      for (int mt = 0; mt < 4; ++mt)
#pragma unroll
        for (int r = 0; r < 4; ++r) {
          const int row = m0 + wm + mt * 16 + qd * 4 + r;
          Cvv[(size_t)row * 512 + col] = f2bf(accV[mt][nt][r] + bc);
        }
    }
  } else {
    // transpose via LDS reuse (staging dead). per-wave 32x40 tile.
    __syncthreads();
    short* ep = &Sh[w * 1280];
    const int lr = lane >> 1, lc16 = (lane & 1) * 16;
#pragma unroll
    for (int pass = 0; pass < 2; ++pass) {
#pragma unroll
      for (int mh = 0; mh < 2; ++mh) {
        const int mt = pass * 2 + mh;
#pragma unroll
        for (int nt = 0; nt < 2; ++nt) {
          const float bc = bv[n0 + wn2 + nt * 16 + ln];
#pragma unroll
          for (int r = 0; r < 4; ++r)
            ep[(nt * 16 + ln) * 40 + mh * 16 + qd * 4 + r] = f2bf(accV[mt][nt][r] + bc);
        }
      }
      LGKM_WAIT();
      const int srow0 = m0 + wm + pass * 32;
      const int bidx = srow0 >> 11;
      const int sloc = (srow0 & 2047) + lc16;
      const int pcol = n0 + wn2 + lr;
      short* outp = Cvv + (size_t)bidx * P_ * S_ + (size_t)pcol * S_ + sloc;
      *(bf16x8*)outp = *(const bf16x8*)&ep[lr * 40 + lc16];
      *(bf16x8*)(outp + 8) = *(const bf16x8*)&ep[lr * 40 + lc16 + 8];
      LGKM_WAIT();
    }
  }
}

// ---------------------------------------------------------------------------
// split-K reduce for Wo: out = sum_z partial[z] + bo[col], fp32
// ---------------------------------------------------------------------------
__global__ __launch_bounds__(256) void reduce_wo(
    const float* __restrict__ partial, const float* __restrict__ bo,
    float* __restrict__ out)
{
  const int idx4 = blockIdx.x * 256 + threadIdx.x;
  float4 s = ((const float4*)bo)[idx4 & 127];
#pragma unroll
  for (int zz = 0; zz < 4; ++zz) {
    float4 p = ((const float4*)partial)[(size_t)zz * 262144 + idx4];
    s.x += p.x; s.y += p.y; s.z += p.z; s.w += p.w;
  }
  ((float4*)out)[idx4] = s;
}

// ---------------------------------------------------------------------------
// self-score + Ls zeroing
// ---------------------------------------------------------------------------
__global__ __launch_bounds__(256) void selfscore(
    const short* __restrict__ qb, const short* __restrict__ mkb,
    float* __restrict__ eself, float* __restrict__ Ls)
{
  const int z = blockIdx.x, t = threadIdx.x;
  const short* qr = qb + ((size_t)z * M_ + t) * P_;
  const short* mr = mkb + ((size_t)(z >> 3) * M_ + t) * P_;
  float s = 0.f;
#pragma unroll 8
  for (int c = 0; c < P_; c += 8) {
    bf16x8 qv = *(const bf16x8*)(qr + c);
    bf16x8 mv = *(const bf16x8*)(mr + c);
#pragma unroll
    for (int j = 0; j < 8; ++j) s += bf2f(qv[j]) * bf2f(mv[j]);
  }
  eself[(size_t)z * M_ + t] = __expf(s * SCALE);
  Ls[(size_t)z * M_ + t] = 0.f;
}

// ---------------------------------------------------------------------------
extern "C" void kernel_launch(void* const* d_in, const int* in_sizes, int n_in,
                              void* d_out, int out_size, void* d_ws, size_t ws_size,
                              hipStream_t stream) {
  const float* input_seq = (const float*)d_in[0];
  const float* memcells  = (const float*)d_in[1];
  const float* Wk = (const float*)d_in[2];
  const float* bk = (const float*)d_in[3];
  const float* Wv = (const float*)d_in[4];
  const float* bv = (const float*)d_in[5];
  const float* Wq = (const float*)d_in[6];
  const float* bq = (const float*)d_in[7];
  const float* Wo = (const float*)d_in[8];
  const float* bo = (const float*)d_in[9];
  float* out = (float*)d_out;

  short* ws = (short*)d_ws;
  size_t o = 0;
  short* valb = ws + o; o += (size_t)B_ * M_ * H_ * P_;      // 8388608
  short* WoT  = ws + o; o += (size_t)(H_ * P_) * P_;          // 2097152
  short* mvb  = ws + o; o += (size_t)B_ * M_ * P_;            // 1048576
  short* mkb  = ws + o; o += (size_t)B_ * M_ * P_;            // 1048576
  short* qb   = ws + o; o += (size_t)B_ * H_ * M_ * P_;       // 8388608
  short* ivT  = ws + o; o += (size_t)B_ * P_ * S_;            // 8388608
  short* ikb  = ws + o; o += (size_t)B_ * S_ * P_;            // 8388608
  float* partial = (float*)(ws + o); o += (size_t)B_ * H_ * M_ * P_;  // 16 MB
  float* eself = (float*)(ws + o); o += 2 * (size_t)B_ * H_ * M_;
  float* Ls    = (float*)(ws + o); o += 2 * (size_t)B_ * H_ * M_;
  short* region2 = ws + o;                                    // Eb region (64 MB)
  short* Ab  = region2;
  short* Mb  = Ab + (size_t)B_ * S_ * D_;
  short* WkT = Mb + (size_t)B_ * M_ * D_;
  short* WvT = WkT + (size_t)D_ * P_;
  short* WqT = WvT + (size_t)D_ * P_;
  short* Eb  = region2;   // overlaps the above (all dead before E is written)

  dim3 blk(256);

  const int n4A = B_ * S_ * D_ / 4;
  const int n4M = B_ * M_ * D_ / 4;
  cast_both<<<dim3((n4A + n4M) / 256), blk, 0, stream>>>(input_seq, Ab, n4A, memcells, Mb);
  wtrans_all<<<dim3(16, 16, 10), blk, 0, stream>>>(Wk, Wv, Wq, WkT, WvT, WqT);
  wtrans_wo<<<dim3(16, 128), blk, 0, stream>>>(Wo, WoT);

  proj_kv<true><<<dim3(8, 128), blk, 0, stream>>>(Ab, WkT, WvT, bk, bv, ikb, ivT);
  proj_kv<false><<<dim3(8, 16), blk, 0, stream>>>(Mb, WkT, WvT, bk, bv, mkb, mvb);

  // q projection: MODE 1, z = h
  gemm128<1, 512, 512, 512, 512><<<dim3(4, 16, 8), blk, 0, stream>>>(
      Mb, WqT, bq, qb, 0, (size_t)D_ * P_, 0, nullptr, nullptr, nullptr);

  // eself + zero Ls (before QK's atomics)
  selfscore<<<dim3(64), blk, 0, stream>>>(qb, mkb, eself, Ls);

  // E = exp(scale * q @ ik^T) + fused row-sum; per-batch 2048x2048, K=512
  qk256<8><<<dim3(8, 8, 8), dim3(512), 0, stream>>>(qb, ikb, Eb, Ls);

  // val = normalize(E @ iv + eself*mv), concat layout; per-batch 2048x512,
  // K=2048; ring-3 counted-vmcnt variant (round-4 best)
  pv128<32><<<dim3(8, 4, 8), dim3(512), 0, stream>>>(Eb, ivT, valb, Ls, eself, mvb);

  // Wo: split-K=4 partials, then reduce+bias
  gemm128<5, 1024, 512, 4096, 4096><<<dim3(4, 16, 4), blk, 0, stream>>>(
      valb, WoT, nullptr, partial, 1024, 1024,
      (size_t)2048 * 512, nullptr, nullptr, nullptr);
  reduce_wo<<<dim3(1024), blk, 0, stream>>>(partial, bo, out);
}

// Round 10
// 295.542 us; speedup vs baseline: 1.1025x; 1.0252x over previous
//
#include <hip/hip_runtime.h>

#define B_ 8
#define S_ 2048
#define M_ 256
#define D_ 512
#define P_ 512
#define H_ 8

#define SCALE 0.044194173824159216f  // 1/sqrt(512)

typedef __attribute__((ext_vector_type(8))) short bf16x8;
typedef __attribute__((ext_vector_type(4))) float f32x4;

static __device__ __forceinline__ float bf2f(short u) {
  union { float f; unsigned int i; } x;
  x.i = ((unsigned int)(unsigned short)u) << 16;
  return x.f;
}
static __device__ __forceinline__ short f2bf(float f) {
  union { float f; unsigned int i; } x;
  x.f = f;
  unsigned int r = (x.i + 0x7FFFu + ((x.i >> 16) & 1u)) >> 16;
  return (short)r;
}

// async global->LDS, 16B per lane; lds base must be wave-uniform
static __device__ __forceinline__ void gll16(const short* g, short* l) {
  __builtin_amdgcn_global_load_lds(
      (const __attribute__((address_space(1))) void*)g,
      (__attribute__((address_space(3))) void*)l, 16, 0, 0);
}

#define LGKM_WAIT() asm volatile("s_waitcnt lgkmcnt(0)" ::: "memory")
#define VMLG_WAIT() asm volatile("s_waitcnt vmcnt(0) lgkmcnt(0)" ::: "memory")
#define RAW_BAR() do { asm volatile("" ::: "memory"); __builtin_amdgcn_s_barrier(); asm volatile("" ::: "memory"); } while (0)

// ---------------------------------------------------------------------------
// prep: ONE dispatch replacing {cast_both, out-bias-init, wtrans_all,
// wtrans_wo}. Flat block-id ranges; every branch is block-uniform.
//   [0, 9216)        cast input_seq+memcells fp32 -> bf16
//   [9216, 10240)    out[i] = bo[i % 512]  (bias init for MODE5 atomics)
//   [10240, 12800)   wtrans_all (z = (bid-10240)/256)
//   [12800, 14848)   wtrans_wo
// ---------------------------------------------------------------------------
__global__ __launch_bounds__(256) void prep(
    const float* __restrict__ inA, short* __restrict__ outA, int n4A,
    const float* __restrict__ inM, short* __restrict__ outM,
    const float* __restrict__ Wk, const float* __restrict__ Wv,
    const float* __restrict__ Wq,
    short* __restrict__ WkT, short* __restrict__ WvT, short* __restrict__ WqT,
    const float* __restrict__ Wo, short* __restrict__ WoT,
    const float* __restrict__ bo, float* __restrict__ out)
{
  __shared__ float tile[32][33];
  int bid = blockIdx.x;
  const int tthr = threadIdx.x;

  if (bid < 9216) {                       // ---- cast path
    int idx = bid * 256 + tthr;
    const float* in = inA;
    short* outp = outA;
    if (idx >= n4A) { idx -= n4A; in = inM; outp = outM; }
    float4 v = ((const float4*)in)[idx];
    short o0 = f2bf(v.x), o1 = f2bf(v.y), o2 = f2bf(v.z), o3 = f2bf(v.w);
    uint2 pk;
    pk.x = (unsigned int)(unsigned short)o0 | ((unsigned int)(unsigned short)o1 << 16);
    pk.y = (unsigned int)(unsigned short)o2 | ((unsigned int)(unsigned short)o3 << 16);
    ((uint2*)outp)[idx] = pk;
    return;
  }
  bid -= 9216;

  if (bid < 1024) {                       // ---- out = bias broadcast
    const int idx4 = bid * 256 + tthr;    // 262144 float4 = 2048x512 fp32
    ((float4*)out)[idx4] = ((const float4*)bo)[idx4 & 127];
    return;
  }
  bid -= 1024;

  const int tx = tthr & 31, ty = tthr >> 5;

  if (bid < 2560) {                       // ---- wtrans_all
    const int z = bid >> 8, rem = bid & 255;
    const int n0 = (rem & 15) * 32, k0 = (rem >> 4) * 32;
    const float* inp;
    short* outp;
    if (z == 0)      { inp = Wk; outp = WkT; }
    else if (z == 1) { inp = Wv; outp = WvT; }
    else             { inp = Wq + (size_t)(z - 2) * 512 * 512;
                       outp = WqT + (size_t)(z - 2) * 512 * 512; }
#pragma unroll
    for (int i = 0; i < 4; ++i)
      tile[ty + 8 * i][tx] = inp[(size_t)(k0 + ty + 8 * i) * 512 + n0 + tx];
    __syncthreads();
#pragma unroll
    for (int i = 0; i < 4; ++i)
      outp[(size_t)(n0 + ty + 8 * i) * 512 + k0 + tx] = f2bf(tile[tx][ty + 8 * i]);
    return;
  }
  bid -= 2560;

  {                                       // ---- wtrans_wo (2048 blocks)
    const int n0 = (bid & 15) * 32, k0 = (bid >> 4) * 32;
#pragma unroll
    for (int i = 0; i < 4; ++i)
      tile[ty + 8 * i][tx] = Wo[(size_t)(k0 + ty + 8 * i) * 512 + n0 + tx];
    __syncthreads();
#pragma unroll
    for (int i = 0; i < 4; ++i)
      WoT[(size_t)(n0 + ty + 8 * i) * 4096 + k0 + tx] = f2bf(tile[tx][ty + 8 * i]);
  }
}

// ---------------------------------------------------------------------------
// 128x128 MFMA GEMM, BK=32, 1-barrier double-buffer loop (r9 schedule).
// MODE 1: q projection (bf16 out, scattered). MODE 5: Wo product --
// epilogue now ATOMIC-ADDS fp32 into out (pre-initialized with bias by
// prep), replacing the 16MB partial write + reduce_wo read (saves ~36 MB
// HBM traffic + 1 dispatch; fp32 add reorder ~1e-6 << 4.9e-4 tolerance).
// ---------------------------------------------------------------------------
template<int MODE, int K, int N, int LDA, int LDB>
__global__ __launch_bounds__(256, 3) void gemm128(
    const short* __restrict__ Abase, const short* __restrict__ Bbase,
    const float* __restrict__ bias, void* __restrict__ Cv,
    const size_t aZ, const size_t bZ,
    float* __restrict__ Ls,
    const float* __restrict__ eselfp, const short* __restrict__ mvbp)
{
  __shared__ short As[8192];   // 2 x 128x32
  __shared__ short Bs[8192];
  const int t = threadIdx.x;
  const int w = t >> 6, lane = t & 63, qd = lane >> 4, ln = lane & 15;
  const int wm = (w & 1) * 64, wn = (w >> 1) * 64;

  const int n0 = blockIdx.x * 128;
  const int m0 = blockIdx.y * 128;
  const int z = blockIdx.z;

  const short* A  = Abase + (size_t)z * aZ;
  const short* Bp = Bbase + (size_t)z * bZ;

  const int rr = t >> 2, g0 = t & 3;
  const int gs0 = g0 ^ ((rr >> 1) & 3);
  const int gs1 = g0 ^ (((rr + 64) >> 1) & 3);
  const short* ga0 = A + (size_t)(m0 + rr) * LDA + gs0 * 8;
  const short* ga1 = A + (size_t)(m0 + rr + 64) * LDA + gs1 * 8;
  const short* gb0 = Bp + (size_t)(n0 + rr) * LDB + gs0 * 8;
  const short* gb1 = Bp + (size_t)(n0 + rr + 64) * LDB + gs1 * 8;

  int aoff[4], boff[4];
#pragma unroll
  for (int mt = 0; mt < 4; ++mt) {
    int r = wm + mt * 16 + ln;
    aoff[mt] = r * 32 + (qd ^ ((r >> 1) & 3)) * 8;
  }
#pragma unroll
  for (int nt = 0; nt < 4; ++nt) {
    int r = wn + nt * 16 + ln;
    boff[nt] = r * 32 + (qd ^ ((r >> 1) & 3)) * 8;
  }

  f32x4 acc[4][4];
#pragma unroll
  for (int mt = 0; mt < 4; ++mt)
#pragma unroll
    for (int nt = 0; nt < 4; ++nt) acc[mt][nt] = (f32x4){0.f, 0.f, 0.f, 0.f};

  // prologue: stage tile0 -> buf0
  gll16(ga0, &As[w * 512]);
  gll16(ga1, &As[2048 + w * 512]);
  gll16(gb0, &Bs[w * 512]);
  gll16(gb1, &Bs[2048 + w * 512]);
  asm volatile("s_waitcnt vmcnt(0)" ::: "memory");
  __builtin_amdgcn_s_barrier();

#pragma unroll 1
  for (int kc = 0; kc < K; kc += 32) {
    const int p = (kc >> 5) & 1;
    short* Ap = &As[p * 4096];
    short* Bq = &Bs[p * 4096];

    bf16x8 af[4], bfr[4];
#pragma unroll
    for (int mt = 0; mt < 4; ++mt) af[mt] = *(const bf16x8*)&Ap[aoff[mt]];
#pragma unroll
    for (int nt = 0; nt < 4; ++nt) bfr[nt] = *(const bf16x8*)&Bq[boff[nt]];

    if (kc + 32 < K) {
      const int nb = (p ^ 1) * 4096;
      gll16(ga0 + kc + 32, &As[nb + w * 512]);
      gll16(ga1 + kc + 32, &As[nb + 2048 + w * 512]);
      gll16(gb0 + kc + 32, &Bs[nb + w * 512]);
      gll16(gb1 + kc + 32, &Bs[nb + 2048 + w * 512]);
    }

    __builtin_amdgcn_s_setprio(1);
#pragma unroll
    for (int mt = 0; mt < 4; ++mt)
#pragma unroll
      for (int nt = 0; nt < 4; ++nt)
        acc[mt][nt] = __builtin_amdgcn_mfma_f32_16x16x32_bf16(af[mt], bfr[nt], acc[mt][nt], 0, 0, 0);
    __builtin_amdgcn_s_setprio(0);

    VMLG_WAIT();
    RAW_BAR();
  }

  if constexpr (MODE == 5) {
#pragma unroll
    for (int nt = 0; nt < 4; ++nt) {
      const int col = n0 + wn + nt * 16 + ln;
#pragma unroll
      for (int mt = 0; mt < 4; ++mt)
#pragma unroll
        for (int r = 0; r < 4; ++r) {
          const int row = m0 + wm + mt * 16 + qd * 4 + r;
          atomicAdd(&((float*)Cv)[(size_t)row * N + col], acc[mt][nt][r]);
        }
    }
  } else {  // MODE 1
#pragma unroll
    for (int nt = 0; nt < 4; ++nt) {
      const int col = n0 + wn + nt * 16 + ln;
      const float bc = bias[512 * z + col];
#pragma unroll
      for (int mt = 0; mt < 4; ++mt)
#pragma unroll
        for (int r = 0; r < 4; ++r) {
          const int row = m0 + wm + mt * 16 + qd * 4 + r;
          const int bidx = row >> 8, ml = row & 255;
          ((short*)Cv)[((size_t)(bidx * H_ + z) * M_ + ml) * N + col] = f2bf(acc[mt][nt][r] + bc);
        }
    }
  }
}

// ---------------------------------------------------------------------------
// QK kernel (r3/r9 structure): 256x256 tile, BK=64, 512 thr (8 waves 2Mx4N,
// wave 128x64). ONE barrier per K-tile; compiler-counted lgkmcnt overlaps
// kk1 reads under kk0 MFMA. Swizzle: chunk c of row r at c^(r&7), staged
// via pre-swizzled global source (verified 0 conflicts).
// ---------------------------------------------------------------------------
template<int NKT>
__global__ __launch_bounds__(512, 2) void qk256(
    const short* __restrict__ Abase, const short* __restrict__ Bbase,
    short* __restrict__ Eb, float* __restrict__ Ls)
{
  __shared__ short lds[65536];   // A: 2buf x [2half][128][64] | B same at +32768
  const int t = threadIdx.x;
  const int w = t >> 6, lane = t & 63, qd = lane >> 4, ln = lane & 15;
  const int wr = w >> 2, wc = w & 3;
  const int b = blockIdx.x;                       // XCD pin: flat id % 8 == b
  const int n0 = blockIdx.y * 256, m0 = blockIdx.z * 256;

  const short* A  = Abase + (size_t)b * (2048 * 512) + (size_t)m0 * 512;
  const short* Bp = Bbase + (size_t)b * (2048 * 512) + (size_t)n0 * 512;

  const int s0 = w * 64 + lane, s1 = s0 + 512;
  const int sr0 = s0 >> 3, sc0 = ((s0 & 7) ^ (sr0 & 7)) * 8;
  const int sr1 = s1 >> 3, sc1 = ((s1 & 7) ^ (sr1 & 7)) * 8;
  auto stage = [&](const short* g, short* lbase) {
    gll16(g + (size_t)sr0 * 512 + sc0, lbase + w * 512);
    gll16(g + (size_t)sr1 * 512 + sc1, lbase + 4096 + w * 512);
  };

  const int cq0 = ((qd    ) ^ (ln & 7)) * 8;
  const int cq1 = ((4 + qd) ^ (ln & 7)) * 8;
  const int brow = (wc & 1) * 64;

  f32x4 acc[8][4];
#pragma unroll
  for (int i = 0; i < 8; ++i)
#pragma unroll
    for (int j = 0; j < 4; ++j) acc[i][j] = (f32x4){0.f, 0.f, 0.f, 0.f};

  // ---- prologue: stage tile0, drain, go
  stage(A,              &lds[0]);
  stage(A + 128 * 512,  &lds[8192]);
  stage(Bp,             &lds[32768]);
  stage(Bp + 128 * 512, &lds[32768 + 8192]);
  asm volatile("s_waitcnt vmcnt(0)" ::: "memory");
  __builtin_amdgcn_s_barrier();

#pragma unroll 1
  for (int kt = 0; kt < NKT; ++kt) {
    const int p = kt & 1;
    short* Ah = &lds[p * 16384 + wr * 8192];
    short* Bh = &lds[32768 + p * 16384 + (wc >> 1) * 8192];

    bf16x8 a0[8], b0[4];
#pragma unroll
    for (int j = 0; j < 4; ++j)
      b0[j] = *(const bf16x8*)&Bh[(brow + j * 16 + ln) * 64 + cq0];
#pragma unroll
    for (int mt = 0; mt < 8; ++mt)
      a0[mt] = *(const bf16x8*)&Ah[(mt * 16 + ln) * 64 + cq0];
    if (kt + 1 < NKT) {
      stage(A  + (size_t)(kt + 1) * 64,             &lds[(p ^ 1) * 16384]);
      stage(A  + 128 * 512 + (size_t)(kt + 1) * 64, &lds[(p ^ 1) * 16384 + 8192]);
      stage(Bp + (size_t)(kt + 1) * 64,             &lds[32768 + (p ^ 1) * 16384]);
      stage(Bp + 128 * 512 + (size_t)(kt + 1) * 64, &lds[32768 + (p ^ 1) * 16384 + 8192]);
    }
    __builtin_amdgcn_s_setprio(1);
#pragma unroll
    for (int mt = 0; mt < 8; ++mt)
#pragma unroll
      for (int j = 0; j < 4; ++j)
        acc[mt][j] = __builtin_amdgcn_mfma_f32_16x16x32_bf16(a0[mt], b0[j], acc[mt][j], 0, 0, 0);
    __builtin_amdgcn_s_setprio(0);

    bf16x8 a1[8], b1[4];
#pragma unroll
    for (int j = 0; j < 4; ++j)
      b1[j] = *(const bf16x8*)&Bh[(brow + j * 16 + ln) * 64 + cq1];
#pragma unroll
    for (int mt = 0; mt < 8; ++mt)
      a1[mt] = *(const bf16x8*)&Ah[(mt * 16 + ln) * 64 + cq1];
    __builtin_amdgcn_s_setprio(1);
#pragma unroll
    for (int mt = 0; mt < 8; ++mt)
#pragma unroll
      for (int j = 0; j < 4; ++j)
        acc[mt][j] = __builtin_amdgcn_mfma_f32_16x16x32_bf16(a1[mt], b1[j], acc[mt][j], 0, 0, 0);
    __builtin_amdgcn_s_setprio(0);

    VMLG_WAIT();
    RAW_BAR();
  }

  // ---- epilogue: exp, rowsum atomics, LDS repack, coalesced stores
#pragma unroll
  for (int i = 0; i < 8; ++i)
#pragma unroll
    for (int j = 0; j < 4; ++j)
#pragma unroll
      for (int r = 0; r < 4; ++r)
        acc[i][j][r] = __expf(acc[i][j][r] * SCALE);
#pragma unroll
  for (int i = 0; i < 8; ++i)
#pragma unroll
    for (int r = 0; r < 4; ++r) {
      float rs = acc[i][0][r] + acc[i][1][r] + acc[i][2][r] + acc[i][3][r];
      rs += __shfl_xor(rs, 1);
      rs += __shfl_xor(rs, 2);
      rs += __shfl_xor(rs, 4);
      rs += __shfl_xor(rs, 8);
      if (ln == 0) {
        const int row = m0 + wr * 128 + i * 16 + qd * 4 + r;
        atomicAdd(&Ls[(size_t)b * 2048 + row], rs);
      }
    }
#pragma unroll
  for (int i = 0; i < 8; ++i)
#pragma unroll
    for (int j = 0; j < 4; ++j)
#pragma unroll
      for (int r = 0; r < 4; ++r) {
        const int row = wr * 128 + i * 16 + qd * 4 + r;
        const int col = wc * 64 + j * 16 + ln;
        lds[row * 256 + (col ^ ((row & 7) << 3))] = f2bf(acc[i][j][r]);
      }
  LGKM_WAIT();
  RAW_BAR();
  short* Cb = Eb + (size_t)b * 2048 * 2048;
#pragma unroll
  for (int it = 0; it < 16; ++it) {
    const int flat = it * 512 + t;
    const int row = flat >> 5, c = flat & 31;
    bf16x8 v = *(const bf16x8*)&lds[row * 256 + ((c ^ (row & 7)) * 8)];
    *(bf16x8*)(Cb + (size_t)(m0 + row) * 2048 + n0 + c * 8) = v;
  }
}

// ---------------------------------------------------------------------------
// PV kernel (r4/r9 structure): 256x128 tile, BK=64, NKT=32, 512 thr,
// wave grid 4Mx2N (wave 64x64). RING-3 LDS (144 KiB), counted boundary
// vmcnt(6). One barrier/tile.
// ---------------------------------------------------------------------------
template<int NKT>
__global__ __launch_bounds__(512, 2) void pv128(
    const short* __restrict__ Abase, const short* __restrict__ Bbase,
    short* __restrict__ valb, const float* __restrict__ Ls,
    const float* __restrict__ eselfp, const short* __restrict__ mvbp)
{
  __shared__ short lds[73728];   // A ring 3x16384 @0, B ring 3x8192 @49152
  const int t = threadIdx.x;
  const int w = t >> 6, lane = t & 63, qd = lane >> 4, ln = lane & 15;
  const int wr = w >> 1, wc = w & 1;              // 4M x 2N
  const int b = blockIdx.x;                       // XCD pin
  const int n0 = blockIdx.y * 128;
  const int bz = blockIdx.z;                      // head tile: m0 = bz*256
  const int m0 = bz * 256;

  const short* A  = Abase + (size_t)b * (2048 * 2048) + (size_t)m0 * 2048;
  const short* Bp = Bbase + (size_t)b * (512 * 2048) + (size_t)n0 * 2048;

  const int s0 = w * 64 + lane, s1 = s0 + 512;
  const int sr0 = s0 >> 3, sc0 = ((s0 & 7) ^ (sr0 & 7)) * 8;
  const int sr1 = s1 >> 3, sc1 = ((s1 & 7) ^ (sr1 & 7)) * 8;
  auto stage = [&](const short* g, short* lbase) {   // 8192 shorts (128 rows)
    gll16(g + (size_t)sr0 * 2048 + sc0, lbase + w * 512);
    gll16(g + (size_t)sr1 * 2048 + sc1, lbase + 4096 + w * 512);
  };

  const int cq0 = ((qd    ) ^ (ln & 7)) * 8;
  const int cq1 = ((4 + qd) ^ (ln & 7)) * 8;

  short* Ar = &lds[0];     short* An = &lds[16384]; short* Aw = &lds[32768];
  short* Br = &lds[49152]; short* Bn = &lds[57344]; short* Bw = &lds[65536];

  f32x4 acc[4][4];
#pragma unroll
  for (int i = 0; i < 4; ++i)
#pragma unroll
    for (int j = 0; j < 4; ++j) acc[i][j] = (f32x4){0.f, 0.f, 0.f, 0.f};

  // ---- prologue: tile0 -> buf0, tile1 -> buf1; wait tile0 only
  stage(A,                   Ar);
  stage(A + 128 * 2048,      Ar + 8192);
  stage(Bp,                  Br);
  stage(A + 64,              An);
  stage(A + 128 * 2048 + 64, An + 8192);
  stage(Bp + 64,             Bn);
  asm volatile("s_waitcnt vmcnt(6)" ::: "memory");
  __builtin_amdgcn_s_barrier();

#pragma unroll 1
  for (int kt = 0; kt < NKT; ++kt) {
    short* Ah = Ar + (wr >> 1) * 8192 + (wr & 1) * 4096;   // wave's 64-row window
    short* Bh = Br;

    bf16x8 a0[4], b0[4];
#pragma unroll
    for (int j = 0; j < 4; ++j)
      b0[j] = *(const bf16x8*)&Bh[(wc * 64 + j * 16 + ln) * 64 + cq0];
#pragma unroll
    for (int mt = 0; mt < 4; ++mt)
      a0[mt] = *(const bf16x8*)&Ah[(mt * 16 + ln) * 64 + cq0];

    if (kt + 2 < NKT) {
      stage(A  + (size_t)(kt + 2) * 64,              Aw);
      stage(A  + 128 * 2048 + (size_t)(kt + 2) * 64, Aw + 8192);
      stage(Bp + (size_t)(kt + 2) * 64,              Bw);
    }

    __builtin_amdgcn_s_setprio(1);
#pragma unroll
    for (int mt = 0; mt < 4; ++mt)
#pragma unroll
      for (int j = 0; j < 4; ++j)
        acc[mt][j] = __builtin_amdgcn_mfma_f32_16x16x32_bf16(a0[mt], b0[j], acc[mt][j], 0, 0, 0);
    __builtin_amdgcn_s_setprio(0);

    bf16x8 a1[4], b1[4];
#pragma unroll
    for (int j = 0; j < 4; ++j)
      b1[j] = *(const bf16x8*)&Bh[(wc * 64 + j * 16 + ln) * 64 + cq1];
#pragma unroll
    for (int mt = 0; mt < 4; ++mt)
      a1[mt] = *(const bf16x8*)&Ah[(mt * 16 + ln) * 64 + cq1];
    __builtin_amdgcn_s_setprio(1);
#pragma unroll
    for (int mt = 0; mt < 4; ++mt)
#pragma unroll
      for (int j = 0; j < 4; ++j)
        acc[mt][j] = __builtin_amdgcn_mfma_f32_16x16x32_bf16(a1[mt], b1[j], acc[mt][j], 0, 0, 0);
    __builtin_amdgcn_s_setprio(0);

    if (kt + 2 < NKT) { asm volatile("s_waitcnt vmcnt(6) lgkmcnt(0)" ::: "memory"); }
    else              { asm volatile("s_waitcnt vmcnt(0) lgkmcnt(0)" ::: "memory"); }
    RAW_BAR();

    short* tA = Ar; Ar = An; An = Aw; Aw = tA;
    short* tB = Br; Br = Bn; Bn = Bw; Bw = tB;
  }

  // ---- epilogue: normalize + self-attn term, LDS repack, coalesced stores
#pragma unroll
  for (int mt = 0; mt < 4; ++mt)
#pragma unroll
    for (int r = 0; r < 4; ++r) {
      const int row = wr * 64 + mt * 16 + qd * 4 + r;   // local row, R = m0+row
      const float es  = eselfp[(size_t)b * 2048 + m0 + row];
      const float inv = 1.f / (es + Ls[(size_t)b * 2048 + m0 + row]);
      const short* mvr = mvbp + ((size_t)(b * 256 + row)) * 512;
#pragma unroll
      for (int j = 0; j < 4; ++j) {
        const int lcol = wc * 64 + j * 16 + ln;
        const float v = (acc[mt][j][r] + es * bf2f(mvr[n0 + lcol])) * inv;
        lds[row * 128 + (lcol ^ ((row & 7) << 3))] = f2bf(v);
      }
    }
  LGKM_WAIT();
  RAW_BAR();
#pragma unroll
  for (int it = 0; it < 8; ++it) {
    const int flat = it * 512 + t;
    const int row = flat >> 4, c = flat & 15;
    bf16x8 v = *(const bf16x8*)&lds[row * 128 + ((c ^ (row & 7)) * 8)];
    *(bf16x8*)(valb + ((size_t)(b * 256 + row)) * 4096 + (size_t)bz * 512 + n0 + c * 8) = v;
  }
}

// ---------------------------------------------------------------------------
// merged K/V projection, BOTH streams in one dispatch: blockIdx.y < 128 ->
// big (input_seq: ikb + transposed ivT), else -> small (memcells: mkb + mvb
// row-major). Block-uniform branch. 1-barrier double-buffer (r9 schedule),
// LDS 32 KiB = 2 x {A 4096, Bk 2048, Bv 2048} shorts.
// ---------------------------------------------------------------------------
__global__ __launch_bounds__(256, 3) void proj_kv(
    const short* __restrict__ Ab, const short* __restrict__ Mb,
    const short* __restrict__ WkT, const short* __restrict__ WvT,
    const float* __restrict__ bk, const float* __restrict__ bv,
    short* __restrict__ ikb, short* __restrict__ ivT,
    short* __restrict__ mkb, short* __restrict__ mvb)
{
  __shared__ short Sh[16384];  // dbuf: base = p*8192; A@0, Bk@4096, Bv@6144
  const int t = threadIdx.x;
  const int w = t >> 6, lane = t & 63, qd = lane >> 4, ln = lane & 15;
  const bool big = blockIdx.y < 128;
  const int n0 = blockIdx.x * 64;
  const int m0 = (big ? blockIdx.y : (blockIdx.y - 128)) * 128;
  const int wm = (w & 1) * 64, wn2 = (w >> 1) * 32;

  const short* A = big ? Ab : Mb;
  short* Ck      = big ? ikb : mkb;

  const int rr = t >> 2, g0 = t & 3;
  const int gs0 = g0 ^ ((rr >> 1) & 3);
  const int gs1 = g0 ^ (((rr + 64) >> 1) & 3);
  const short* ga0 = A + (size_t)(m0 + rr) * 512 + gs0 * 8;
  const short* ga1 = A + (size_t)(m0 + rr + 64) * 512 + gs1 * 8;
  const short* gbk = WkT + (size_t)(n0 + rr) * 512 + gs0 * 8;
  const short* gbv = WvT + (size_t)(n0 + rr) * 512 + gs0 * 8;

  int aoff[4], boff[2];
#pragma unroll
  for (int mt = 0; mt < 4; ++mt) {
    int r = wm + mt * 16 + ln;
    aoff[mt] = r * 32 + (qd ^ ((r >> 1) & 3)) * 8;
  }
#pragma unroll
  for (int nt = 0; nt < 2; ++nt) {
    int r = wn2 + nt * 16 + ln;
    boff[nt] = r * 32 + (qd ^ ((r >> 1) & 3)) * 8;
  }

  f32x4 accK[4][2], accV[4][2];
#pragma unroll
  for (int mt = 0; mt < 4; ++mt)
#pragma unroll
    for (int nt = 0; nt < 2; ++nt) {
      accK[mt][nt] = (f32x4){0.f, 0.f, 0.f, 0.f};
      accV[mt][nt] = (f32x4){0.f, 0.f, 0.f, 0.f};
    }

  // prologue: stage tile0 -> buf0
  gll16(ga0, &Sh[w * 512]);
  gll16(ga1, &Sh[2048 + w * 512]);
  gll16(gbk, &Sh[4096 + w * 512]);
  gll16(gbv, &Sh[6144 + w * 512]);
  asm volatile("s_waitcnt vmcnt(0)" ::: "memory");
  __builtin_amdgcn_s_barrier();

#pragma unroll 1
  for (int kc = 0; kc < 512; kc += 32) {
    const int base = ((kc >> 5) & 1) * 8192;

    bf16x8 af[4], bkf[2], bvf[2];
#pragma unroll
    for (int mt = 0; mt < 4; ++mt) af[mt] = *(const bf16x8*)&Sh[base + aoff[mt]];
#pragma unroll
    for (int nt = 0; nt < 2; ++nt) {
      bkf[nt] = *(const bf16x8*)&Sh[base + 4096 + boff[nt]];
      bvf[nt] = *(const bf16x8*)&Sh[base + 6144 + boff[nt]];
    }

    if (kc + 32 < 512) {
      const int nb = base ^ 8192;
      gll16(ga0 + kc + 32, &Sh[nb + w * 512]);
      gll16(ga1 + kc + 32, &Sh[nb + 2048 + w * 512]);
      gll16(gbk + kc + 32, &Sh[nb + 4096 + w * 512]);
      gll16(gbv + kc + 32, &Sh[nb + 6144 + w * 512]);
    }

    __builtin_amdgcn_s_setprio(1);
#pragma unroll
    for (int mt = 0; mt < 4; ++mt)
#pragma unroll
      for (int nt = 0; nt < 2; ++nt) {
        accK[mt][nt] = __builtin_amdgcn_mfma_f32_16x16x32_bf16(af[mt], bkf[nt], accK[mt][nt], 0, 0, 0);
        accV[mt][nt] = __builtin_amdgcn_mfma_f32_16x16x32_bf16(af[mt], bvf[nt], accV[mt][nt], 0, 0, 0);
      }
    __builtin_amdgcn_s_setprio(0);

    VMLG_WAIT();
    RAW_BAR();
  }

  // ---- K epilogue: direct scattered stores
#pragma unroll
  for (int nt = 0; nt < 2; ++nt) {
    const int col = n0 + wn2 + nt * 16 + ln;
    const float bc = bk[col];
#pragma unroll
    for (int mt = 0; mt < 4; ++mt)
#pragma unroll
      for (int r = 0; r < 4; ++r) {
        const int row = m0 + wm + mt * 16 + qd * 4 + r;
        Ck[(size_t)row * 512 + col] = f2bf(accK[mt][nt][r] + bc);
      }
  }

  // ---- V epilogue
  if (!big) {
#pragma unroll
    for (int nt = 0; nt < 2; ++nt) {
      const int col = n0 + wn2 + nt * 16 + ln;
      const float bc = bv[col];
#pragma unroll
      for (int mt = 0; mt < 4; ++mt)
#pragma unroll
        for (int r = 0; r < 4; ++r) {
          const int row = m0 + wm + mt * 16 + qd * 4 + r;
          mvb[(size_t)row * 512 + col] = f2bf(accV[mt][nt][r] + bc);
        }
    }
  } else {
    // transpose via LDS reuse (staging dead). per-wave 32x40 tile.
    __syncthreads();
    short* ep = &Sh[w * 1280];
    const int lr = lane >> 1, lc16 = (lane & 1) * 16;
#pragma unroll
    for (int pass = 0; pass < 2; ++pass) {
#pragma unroll
      for (int mh = 0; mh < 2; ++mh) {
        const int mt = pass * 2 + mh;
#pragma unroll
        for (int nt = 0; nt < 2; ++nt) {
          const float bc = bv[n0 + wn2 + nt * 16 + ln];
#pragma unroll
          for (int r = 0; r < 4; ++r)
            ep[(nt * 16 + ln) * 40 + mh * 16 + qd * 4 + r] = f2bf(accV[mt][nt][r] + bc);
        }
      }
      LGKM_WAIT();
      const int srow0 = m0 + wm + pass * 32;
      const int bidx = srow0 >> 11;
      const int sloc = (srow0 & 2047) + lc16;
      const int pcol = n0 + wn2 + lr;
      short* outp = ivT + (size_t)bidx * P_ * S_ + (size_t)pcol * S_ + sloc;
      *(bf16x8*)outp = *(const bf16x8*)&ep[lr * 40 + lc16];
      *(bf16x8*)(outp + 8) = *(const bf16x8*)&ep[lr * 40 + lc16 + 8];
      LGKM_WAIT();
    }
  }
}

// ---------------------------------------------------------------------------
// self-score + Ls zeroing
// ---------------------------------------------------------------------------
__global__ __launch_bounds__(256) void selfscore(
    const short* __restrict__ qb, const short* __restrict__ mkb,
    float* __restrict__ eself, float* __restrict__ Ls)
{
  const int z = blockIdx.x, t = threadIdx.x;
  const short* qr = qb + ((size_t)z * M_ + t) * P_;
  const short* mr = mkb + ((size_t)(z >> 3) * M_ + t) * P_;
  float s = 0.f;
#pragma unroll 8
  for (int c = 0; c < P_; c += 8) {
    bf16x8 qv = *(const bf16x8*)(qr + c);
    bf16x8 mv = *(const bf16x8*)(mr + c);
#pragma unroll
    for (int j = 0; j < 8; ++j) s += bf2f(qv[j]) * bf2f(mv[j]);
  }
  eself[(size_t)z * M_ + t] = __expf(s * SCALE);
  Ls[(size_t)z * M_ + t] = 0.f;
}

// ---------------------------------------------------------------------------
extern "C" void kernel_launch(void* const* d_in, const int* in_sizes, int n_in,
                              void* d_out, int out_size, void* d_ws, size_t ws_size,
                              hipStream_t stream) {
  const float* input_seq = (const float*)d_in[0];
  const float* memcells  = (const float*)d_in[1];
  const float* Wk = (const float*)d_in[2];
  const float* bk = (const float*)d_in[3];
  const float* Wv = (const float*)d_in[4];
  const float* bv = (const float*)d_in[5];
  const float* Wq = (const float*)d_in[6];
  const float* bq = (const float*)d_in[7];
  const float* Wo = (const float*)d_in[8];
  const float* bo = (const float*)d_in[9];
  float* out = (float*)d_out;

  short* ws = (short*)d_ws;
  size_t o = 0;
  short* valb = ws + o; o += (size_t)B_ * M_ * H_ * P_;      // 8388608
  short* WoT  = ws + o; o += (size_t)(H_ * P_) * P_;          // 2097152
  short* mvb  = ws + o; o += (size_t)B_ * M_ * P_;            // 1048576
  short* mkb  = ws + o; o += (size_t)B_ * M_ * P_;            // 1048576
  short* qb   = ws + o; o += (size_t)B_ * H_ * M_ * P_;       // 8388608
  short* ivT  = ws + o; o += (size_t)B_ * P_ * S_;            // 8388608
  short* ikb  = ws + o; o += (size_t)B_ * S_ * P_;            // 8388608
  float* eself = (float*)(ws + o); o += 2 * (size_t)B_ * H_ * M_;
  float* Ls    = (float*)(ws + o); o += 2 * (size_t)B_ * H_ * M_;
  short* region2 = ws + o;                                    // Eb region (64 MB)
  short* Ab  = region2;
  short* Mb  = Ab + (size_t)B_ * S_ * D_;
  short* WkT = Mb + (size_t)B_ * M_ * D_;
  short* WvT = WkT + (size_t)D_ * P_;
  short* WqT = WvT + (size_t)D_ * P_;
  short* Eb  = region2;   // overlaps the above (all dead before E is written)

  dim3 blk(256);

  // prep: casts + out-bias-init + all weight transposes in ONE dispatch
  const int n4A = B_ * S_ * D_ / 4;   // 2097152
  const int n4M = B_ * M_ * D_ / 4;   // 262144
  prep<<<dim3(14848), blk, 0, stream>>>(
      input_seq, Ab, n4A, memcells, Mb,
      Wk, Wv, Wq, WkT, WvT, WqT, Wo, WoT, bo, out);

  // merged K/V projections, both streams in one dispatch
  proj_kv<<<dim3(8, 144), blk, 0, stream>>>(
      Ab, Mb, WkT, WvT, bk, bv, ikb, ivT, mkb, mvb);

  // q projection: MODE 1, z = h
  gemm128<1, 512, 512, 512, 512><<<dim3(4, 16, 8), blk, 0, stream>>>(
      Mb, WqT, bq, qb, 0, (size_t)D_ * P_, nullptr, nullptr, nullptr);

  // eself + zero Ls (before QK's atomics)
  selfscore<<<dim3(64), blk, 0, stream>>>(qb, mkb, eself, Ls);

  // E = exp(scale * q @ ik^T) + fused row-sum; per-batch 2048x2048, K=512
  qk256<8><<<dim3(8, 8, 8), dim3(512), 0, stream>>>(qb, ikb, Eb, Ls);

  // val = normalize(E @ iv + eself*mv), concat layout; per-batch 2048x512
  pv128<32><<<dim3(8, 4, 8), dim3(512), 0, stream>>>(Eb, ivT, valb, Ls, eself, mvb);

  // Wo: split-K=4, atomicAdd directly into out (bias pre-filled by prep)
  gemm128<5, 1024, 512, 4096, 4096><<<dim3(4, 16, 4), blk, 0, stream>>>(
      valb, WoT, nullptr, out, 1024, 1024, nullptr, nullptr, nullptr);
}

// Round 11
// 285.306 us; speedup vs baseline: 1.1420x; 1.0359x over previous
//
#include <hip/hip_runtime.h>

#define B_ 8
#define S_ 2048
#define M_ 256
#define D_ 512
#define P_ 512
#define H_ 8

#define SCALE 0.044194173824159216f  // 1/sqrt(512)

typedef __attribute__((ext_vector_type(8))) short bf16x8;
typedef __attribute__((ext_vector_type(4))) float f32x4;

static __device__ __forceinline__ float bf2f(short u) {
  union { float f; unsigned int i; } x;
  x.i = ((unsigned int)(unsigned short)u) << 16;
  return x.f;
}
static __device__ __forceinline__ short f2bf(float f) {
  union { float f; unsigned int i; } x;
  x.f = f;
  unsigned int r = (x.i + 0x7FFFu + ((x.i >> 16) & 1u)) >> 16;
  return (short)r;
}

// async global->LDS, 16B per lane; lds base must be wave-uniform
static __device__ __forceinline__ void gll16(const short* g, short* l) {
  __builtin_amdgcn_global_load_lds(
      (const __attribute__((address_space(1))) void*)g,
      (__attribute__((address_space(3))) void*)l, 16, 0, 0);
}

#define LGKM_WAIT() asm volatile("s_waitcnt lgkmcnt(0)" ::: "memory")
#define VMLG_WAIT() asm volatile("s_waitcnt vmcnt(0) lgkmcnt(0)" ::: "memory")
#define RAW_BAR() do { asm volatile("" ::: "memory"); __builtin_amdgcn_s_barrier(); asm volatile("" ::: "memory"); } while (0)

// ---------------------------------------------------------------------------
// prep: ONE dispatch replacing {cast_both, out-bias-init, wtrans_all,
// wtrans_wo}. Flat block-id ranges; every branch is block-uniform.
// ---------------------------------------------------------------------------
__global__ __launch_bounds__(256) void prep(
    const float* __restrict__ inA, short* __restrict__ outA, int n4A,
    const float* __restrict__ inM, short* __restrict__ outM,
    const float* __restrict__ Wk, const float* __restrict__ Wv,
    const float* __restrict__ Wq,
    short* __restrict__ WkT, short* __restrict__ WvT, short* __restrict__ WqT,
    const float* __restrict__ Wo, short* __restrict__ WoT,
    const float* __restrict__ bo, float* __restrict__ out)
{
  __shared__ float tile[32][33];
  int bid = blockIdx.x;
  const int tthr = threadIdx.x;

  if (bid < 9216) {                       // ---- cast path
    int idx = bid * 256 + tthr;
    const float* in = inA;
    short* outp = outA;
    if (idx >= n4A) { idx -= n4A; in = inM; outp = outM; }
    float4 v = ((const float4*)in)[idx];
    short o0 = f2bf(v.x), o1 = f2bf(v.y), o2 = f2bf(v.z), o3 = f2bf(v.w);
    uint2 pk;
    pk.x = (unsigned int)(unsigned short)o0 | ((unsigned int)(unsigned short)o1 << 16);
    pk.y = (unsigned int)(unsigned short)o2 | ((unsigned int)(unsigned short)o3 << 16);
    ((uint2*)outp)[idx] = pk;
    return;
  }
  bid -= 9216;

  if (bid < 1024) {                       // ---- out = bias broadcast
    const int idx4 = bid * 256 + tthr;    // 262144 float4 = 2048x512 fp32
    ((float4*)out)[idx4] = ((const float4*)bo)[idx4 & 127];
    return;
  }
  bid -= 1024;

  const int tx = tthr & 31, ty = tthr >> 5;

  if (bid < 2560) {                       // ---- wtrans_all
    const int z = bid >> 8, rem = bid & 255;
    const int n0 = (rem & 15) * 32, k0 = (rem >> 4) * 32;
    const float* inp;
    short* outp;
    if (z == 0)      { inp = Wk; outp = WkT; }
    else if (z == 1) { inp = Wv; outp = WvT; }
    else             { inp = Wq + (size_t)(z - 2) * 512 * 512;
                       outp = WqT + (size_t)(z - 2) * 512 * 512; }
#pragma unroll
    for (int i = 0; i < 4; ++i)
      tile[ty + 8 * i][tx] = inp[(size_t)(k0 + ty + 8 * i) * 512 + n0 + tx];
    __syncthreads();
#pragma unroll
    for (int i = 0; i < 4; ++i)
      outp[(size_t)(n0 + ty + 8 * i) * 512 + k0 + tx] = f2bf(tile[tx][ty + 8 * i]);
    return;
  }
  bid -= 2560;

  {                                       // ---- wtrans_wo (2048 blocks)
    const int n0 = (bid & 15) * 32, k0 = (bid >> 4) * 32;
#pragma unroll
    for (int i = 0; i < 4; ++i)
      tile[ty + 8 * i][tx] = Wo[(size_t)(k0 + ty + 8 * i) * 512 + n0 + tx];
    __syncthreads();
#pragma unroll
    for (int i = 0; i < 4; ++i)
      WoT[(size_t)(n0 + ty + 8 * i) * 4096 + k0 + tx] = f2bf(tile[tx][ty + 8 * i]);
  }
}

// ---------------------------------------------------------------------------
// 128x128 MFMA GEMM, BK=32, 1-barrier double-buffer loop. MODE 5 only now
// (Wo product): epilogue atomicAdds fp32 into out (bias pre-filled by prep).
// (MODE 1 q-projection moved into the merged projq dispatch.)
// ---------------------------------------------------------------------------
template<int MODE, int K, int N, int LDA, int LDB>
__global__ __launch_bounds__(256, 3) void gemm128(
    const short* __restrict__ Abase, const short* __restrict__ Bbase,
    const float* __restrict__ bias, void* __restrict__ Cv,
    const size_t aZ, const size_t bZ,
    float* __restrict__ Ls,
    const float* __restrict__ eselfp, const short* __restrict__ mvbp)
{
  __shared__ short As[8192];   // 2 x 128x32
  __shared__ short Bs[8192];
  const int t = threadIdx.x;
  const int w = t >> 6, lane = t & 63, qd = lane >> 4, ln = lane & 15;
  const int wm = (w & 1) * 64, wn = (w >> 1) * 64;

  const int n0 = blockIdx.x * 128;
  const int m0 = blockIdx.y * 128;
  const int z = blockIdx.z;

  const short* A  = Abase + (size_t)z * aZ;
  const short* Bp = Bbase + (size_t)z * bZ;

  const int rr = t >> 2, g0 = t & 3;
  const int gs0 = g0 ^ ((rr >> 1) & 3);
  const int gs1 = g0 ^ (((rr + 64) >> 1) & 3);
  const short* ga0 = A + (size_t)(m0 + rr) * LDA + gs0 * 8;
  const short* ga1 = A + (size_t)(m0 + rr + 64) * LDA + gs1 * 8;
  const short* gb0 = Bp + (size_t)(n0 + rr) * LDB + gs0 * 8;
  const short* gb1 = Bp + (size_t)(n0 + rr + 64) * LDB + gs1 * 8;

  int aoff[4], boff[4];
#pragma unroll
  for (int mt = 0; mt < 4; ++mt) {
    int r = wm + mt * 16 + ln;
    aoff[mt] = r * 32 + (qd ^ ((r >> 1) & 3)) * 8;
  }
#pragma unroll
  for (int nt = 0; nt < 4; ++nt) {
    int r = wn + nt * 16 + ln;
    boff[nt] = r * 32 + (qd ^ ((r >> 1) & 3)) * 8;
  }

  f32x4 acc[4][4];
#pragma unroll
  for (int mt = 0; mt < 4; ++mt)
#pragma unroll
    for (int nt = 0; nt < 4; ++nt) acc[mt][nt] = (f32x4){0.f, 0.f, 0.f, 0.f};

  // prologue: stage tile0 -> buf0
  gll16(ga0, &As[w * 512]);
  gll16(ga1, &As[2048 + w * 512]);
  gll16(gb0, &Bs[w * 512]);
  gll16(gb1, &Bs[2048 + w * 512]);
  asm volatile("s_waitcnt vmcnt(0)" ::: "memory");
  __builtin_amdgcn_s_barrier();

#pragma unroll 1
  for (int kc = 0; kc < K; kc += 32) {
    const int p = (kc >> 5) & 1;
    short* Ap = &As[p * 4096];
    short* Bq = &Bs[p * 4096];

    bf16x8 af[4], bfr[4];
#pragma unroll
    for (int mt = 0; mt < 4; ++mt) af[mt] = *(const bf16x8*)&Ap[aoff[mt]];
#pragma unroll
    for (int nt = 0; nt < 4; ++nt) bfr[nt] = *(const bf16x8*)&Bq[boff[nt]];

    if (kc + 32 < K) {
      const int nb = (p ^ 1) * 4096;
      gll16(ga0 + kc + 32, &As[nb + w * 512]);
      gll16(ga1 + kc + 32, &As[nb + 2048 + w * 512]);
      gll16(gb0 + kc + 32, &Bs[nb + w * 512]);
      gll16(gb1 + kc + 32, &Bs[nb + 2048 + w * 512]);
    }

    __builtin_amdgcn_s_setprio(1);
#pragma unroll
    for (int mt = 0; mt < 4; ++mt)
#pragma unroll
      for (int nt = 0; nt < 4; ++nt)
        acc[mt][nt] = __builtin_amdgcn_mfma_f32_16x16x32_bf16(af[mt], bfr[nt], acc[mt][nt], 0, 0, 0);
    __builtin_amdgcn_s_setprio(0);

    VMLG_WAIT();
    RAW_BAR();
  }

  if constexpr (MODE == 5) {
#pragma unroll
    for (int nt = 0; nt < 4; ++nt) {
      const int col = n0 + wn + nt * 16 + ln;
#pragma unroll
      for (int mt = 0; mt < 4; ++mt)
#pragma unroll
        for (int r = 0; r < 4; ++r) {
          const int row = m0 + wm + mt * 16 + qd * 4 + r;
          atomicAdd(&((float*)Cv)[(size_t)row * N + col], acc[mt][nt][r]);
        }
    }
  } else {  // MODE 1 (unused in this round's launch; kept for completeness)
#pragma unroll
    for (int nt = 0; nt < 4; ++nt) {
      const int col = n0 + wn + nt * 16 + ln;
      const float bc = bias[512 * z + col];
#pragma unroll
      for (int mt = 0; mt < 4; ++mt)
#pragma unroll
        for (int r = 0; r < 4; ++r) {
          const int row = m0 + wm + mt * 16 + qd * 4 + r;
          const int bidx = row >> 8, ml = row & 255;
          ((short*)Cv)[((size_t)(bidx * H_ + z) * M_ + ml) * N + col] = f2bf(acc[mt][nt][r] + bc);
        }
    }
  }
}

// ---------------------------------------------------------------------------
// QK kernel (r3/r10 structure): 256x256 tile, BK=64, 512 thr (8 waves 2Mx4N,
// wave 128x64). ONE barrier per K-tile; compiler-counted lgkmcnt overlaps
// kk1 reads under kk0 MFMA. Swizzle: chunk c of row r at c^(r&7), staged
// via pre-swizzled global source (verified 0 conflicts).
// ---------------------------------------------------------------------------
template<int NKT>
__global__ __launch_bounds__(512, 2) void qk256(
    const short* __restrict__ Abase, const short* __restrict__ Bbase,
    short* __restrict__ Eb, float* __restrict__ Ls)
{
  __shared__ short lds[65536];   // A: 2buf x [2half][128][64] | B same at +32768
  const int t = threadIdx.x;
  const int w = t >> 6, lane = t & 63, qd = lane >> 4, ln = lane & 15;
  const int wr = w >> 2, wc = w & 3;
  const int b = blockIdx.x;                       // XCD pin: flat id % 8 == b
  const int n0 = blockIdx.y * 256, m0 = blockIdx.z * 256;

  const short* A  = Abase + (size_t)b * (2048 * 512) + (size_t)m0 * 512;
  const short* Bp = Bbase + (size_t)b * (2048 * 512) + (size_t)n0 * 512;

  const int s0 = w * 64 + lane, s1 = s0 + 512;
  const int sr0 = s0 >> 3, sc0 = ((s0 & 7) ^ (sr0 & 7)) * 8;
  const int sr1 = s1 >> 3, sc1 = ((s1 & 7) ^ (sr1 & 7)) * 8;
  auto stage = [&](const short* g, short* lbase) {
    gll16(g + (size_t)sr0 * 512 + sc0, lbase + w * 512);
    gll16(g + (size_t)sr1 * 512 + sc1, lbase + 4096 + w * 512);
  };

  const int cq0 = ((qd    ) ^ (ln & 7)) * 8;
  const int cq1 = ((4 + qd) ^ (ln & 7)) * 8;
  const int brow = (wc & 1) * 64;

  f32x4 acc[8][4];
#pragma unroll
  for (int i = 0; i < 8; ++i)
#pragma unroll
    for (int j = 0; j < 4; ++j) acc[i][j] = (f32x4){0.f, 0.f, 0.f, 0.f};

  // ---- prologue: stage tile0, drain, go
  stage(A,              &lds[0]);
  stage(A + 128 * 512,  &lds[8192]);
  stage(Bp,             &lds[32768]);
  stage(Bp + 128 * 512, &lds[32768 + 8192]);
  asm volatile("s_waitcnt vmcnt(0)" ::: "memory");
  __builtin_amdgcn_s_barrier();

#pragma unroll 1
  for (int kt = 0; kt < NKT; ++kt) {
    const int p = kt & 1;
    short* Ah = &lds[p * 16384 + wr * 8192];
    short* Bh = &lds[32768 + p * 16384 + (wc >> 1) * 8192];

    bf16x8 a0[8], b0[4];
#pragma unroll
    for (int j = 0; j < 4; ++j)
      b0[j] = *(const bf16x8*)&Bh[(brow + j * 16 + ln) * 64 + cq0];
#pragma unroll
    for (int mt = 0; mt < 8; ++mt)
      a0[mt] = *(const bf16x8*)&Ah[(mt * 16 + ln) * 64 + cq0];
    if (kt + 1 < NKT) {
      stage(A  + (size_t)(kt + 1) * 64,             &lds[(p ^ 1) * 16384]);
      stage(A  + 128 * 512 + (size_t)(kt + 1) * 64, &lds[(p ^ 1) * 16384 + 8192]);
      stage(Bp + (size_t)(kt + 1) * 64,             &lds[32768 + (p ^ 1) * 16384]);
      stage(Bp + 128 * 512 + (size_t)(kt + 1) * 64, &lds[32768 + (p ^ 1) * 16384 + 8192]);
    }
    __builtin_amdgcn_s_setprio(1);
#pragma unroll
    for (int mt = 0; mt < 8; ++mt)
#pragma unroll
      for (int j = 0; j < 4; ++j)
        acc[mt][j] = __builtin_amdgcn_mfma_f32_16x16x32_bf16(a0[mt], b0[j], acc[mt][j], 0, 0, 0);
    __builtin_amdgcn_s_setprio(0);

    bf16x8 a1[8], b1[4];
#pragma unroll
    for (int j = 0; j < 4; ++j)
      b1[j] = *(const bf16x8*)&Bh[(brow + j * 16 + ln) * 64 + cq1];
#pragma unroll
    for (int mt = 0; mt < 8; ++mt)
      a1[mt] = *(const bf16x8*)&Ah[(mt * 16 + ln) * 64 + cq1];
    __builtin_amdgcn_s_setprio(1);
#pragma unroll
    for (int mt = 0; mt < 8; ++mt)
#pragma unroll
      for (int j = 0; j < 4; ++j)
        acc[mt][j] = __builtin_amdgcn_mfma_f32_16x16x32_bf16(a1[mt], b1[j], acc[mt][j], 0, 0, 0);
    __builtin_amdgcn_s_setprio(0);

    VMLG_WAIT();
    RAW_BAR();
  }

  // ---- epilogue: exp, rowsum atomics, LDS repack, coalesced stores
#pragma unroll
  for (int i = 0; i < 8; ++i)
#pragma unroll
    for (int j = 0; j < 4; ++j)
#pragma unroll
      for (int r = 0; r < 4; ++r)
        acc[i][j][r] = __expf(acc[i][j][r] * SCALE);
#pragma unroll
  for (int i = 0; i < 8; ++i)
#pragma unroll
    for (int r = 0; r < 4; ++r) {
      float rs = acc[i][0][r] + acc[i][1][r] + acc[i][2][r] + acc[i][3][r];
      rs += __shfl_xor(rs, 1);
      rs += __shfl_xor(rs, 2);
      rs += __shfl_xor(rs, 4);
      rs += __shfl_xor(rs, 8);
      if (ln == 0) {
        const int row = m0 + wr * 128 + i * 16 + qd * 4 + r;
        atomicAdd(&Ls[(size_t)b * 2048 + row], rs);
      }
    }
#pragma unroll
  for (int i = 0; i < 8; ++i)
#pragma unroll
    for (int j = 0; j < 4; ++j)
#pragma unroll
      for (int r = 0; r < 4; ++r) {
        const int row = wr * 128 + i * 16 + qd * 4 + r;
        const int col = wc * 64 + j * 16 + ln;
        lds[row * 256 + (col ^ ((row & 7) << 3))] = f2bf(acc[i][j][r]);
      }
  LGKM_WAIT();
  RAW_BAR();
  short* Cb = Eb + (size_t)b * 2048 * 2048;
#pragma unroll
  for (int it = 0; it < 16; ++it) {
    const int flat = it * 512 + t;
    const int row = flat >> 5, c = flat & 31;
    bf16x8 v = *(const bf16x8*)&lds[row * 256 + ((c ^ (row & 7)) * 8)];
    *(bf16x8*)(Cb + (size_t)(m0 + row) * 2048 + n0 + c * 8) = v;
  }
}

// ---------------------------------------------------------------------------
// PV kernel (r4/r10 structure): 256x128 tile, BK=64, NKT=32, 512 thr,
// wave grid 4Mx2N (wave 64x64). RING-3 LDS (144 KiB), counted boundary
// vmcnt(6). One barrier/tile.
// ---------------------------------------------------------------------------
template<int NKT>
__global__ __launch_bounds__(512, 2) void pv128(
    const short* __restrict__ Abase, const short* __restrict__ Bbase,
    short* __restrict__ valb, const float* __restrict__ Ls,
    const float* __restrict__ eselfp, const short* __restrict__ mvbp)
{
  __shared__ short lds[73728];   // A ring 3x16384 @0, B ring 3x8192 @49152
  const int t = threadIdx.x;
  const int w = t >> 6, lane = t & 63, qd = lane >> 4, ln = lane & 15;
  const int wr = w >> 1, wc = w & 1;              // 4M x 2N
  const int b = blockIdx.x;                       // XCD pin
  const int n0 = blockIdx.y * 128;
  const int bz = blockIdx.z;                      // head tile: m0 = bz*256
  const int m0 = bz * 256;

  const short* A  = Abase + (size_t)b * (2048 * 2048) + (size_t)m0 * 2048;
  const short* Bp = Bbase + (size_t)b * (512 * 2048) + (size_t)n0 * 2048;

  const int s0 = w * 64 + lane, s1 = s0 + 512;
  const int sr0 = s0 >> 3, sc0 = ((s0 & 7) ^ (sr0 & 7)) * 8;
  const int sr1 = s1 >> 3, sc1 = ((s1 & 7) ^ (sr1 & 7)) * 8;
  auto stage = [&](const short* g, short* lbase) {   // 8192 shorts (128 rows)
    gll16(g + (size_t)sr0 * 2048 + sc0, lbase + w * 512);
    gll16(g + (size_t)sr1 * 2048 + sc1, lbase + 4096 + w * 512);
  };

  const int cq0 = ((qd    ) ^ (ln & 7)) * 8;
  const int cq1 = ((4 + qd) ^ (ln & 7)) * 8;

  short* Ar = &lds[0];     short* An = &lds[16384]; short* Aw = &lds[32768];
  short* Br = &lds[49152]; short* Bn = &lds[57344]; short* Bw = &lds[65536];

  f32x4 acc[4][4];
#pragma unroll
  for (int i = 0; i < 4; ++i)
#pragma unroll
    for (int j = 0; j < 4; ++j) acc[i][j] = (f32x4){0.f, 0.f, 0.f, 0.f};

  // ---- prologue: tile0 -> buf0, tile1 -> buf1; wait tile0 only
  stage(A,                   Ar);
  stage(A + 128 * 2048,      Ar + 8192);
  stage(Bp,                  Br);
  stage(A + 64,              An);
  stage(A + 128 * 2048 + 64, An + 8192);
  stage(Bp + 64,             Bn);
  asm volatile("s_waitcnt vmcnt(6)" ::: "memory");
  __builtin_amdgcn_s_barrier();

#pragma unroll 1
  for (int kt = 0; kt < NKT; ++kt) {
    short* Ah = Ar + (wr >> 1) * 8192 + (wr & 1) * 4096;   // wave's 64-row window
    short* Bh = Br;

    bf16x8 a0[4], b0[4];
#pragma unroll
    for (int j = 0; j < 4; ++j)
      b0[j] = *(const bf16x8*)&Bh[(wc * 64 + j * 16 + ln) * 64 + cq0];
#pragma unroll
    for (int mt = 0; mt < 4; ++mt)
      a0[mt] = *(const bf16x8*)&Ah[(mt * 16 + ln) * 64 + cq0];

    if (kt + 2 < NKT) {
      stage(A  + (size_t)(kt + 2) * 64,              Aw);
      stage(A  + 128 * 2048 + (size_t)(kt + 2) * 64, Aw + 8192);
      stage(Bp + (size_t)(kt + 2) * 64,              Bw);
    }

    __builtin_amdgcn_s_setprio(1);
#pragma unroll
    for (int mt = 0; mt < 4; ++mt)
#pragma unroll
      for (int j = 0; j < 4; ++j)
        acc[mt][j] = __builtin_amdgcn_mfma_f32_16x16x32_bf16(a0[mt], b0[j], acc[mt][j], 0, 0, 0);
    __builtin_amdgcn_s_setprio(0);

    bf16x8 a1[4], b1[4];
#pragma unroll
    for (int j = 0; j < 4; ++j)
      b1[j] = *(const bf16x8*)&Bh[(wc * 64 + j * 16 + ln) * 64 + cq1];
#pragma unroll
    for (int mt = 0; mt < 4; ++mt)
      a1[mt] = *(const bf16x8*)&Ah[(mt * 16 + ln) * 64 + cq1];
    __builtin_amdgcn_s_setprio(1);
#pragma unroll
    for (int mt = 0; mt < 4; ++mt)
#pragma unroll
      for (int j = 0; j < 4; ++j)
        acc[mt][j] = __builtin_amdgcn_mfma_f32_16x16x32_bf16(a1[mt], b1[j], acc[mt][j], 0, 0, 0);
    __builtin_amdgcn_s_setprio(0);

    if (kt + 2 < NKT) { asm volatile("s_waitcnt vmcnt(6) lgkmcnt(0)" ::: "memory"); }
    else              { asm volatile("s_waitcnt vmcnt(0) lgkmcnt(0)" ::: "memory"); }
    RAW_BAR();

    short* tA = Ar; Ar = An; An = Aw; Aw = tA;
    short* tB = Br; Br = Bn; Bn = Bw; Bw = tB;
  }

  // ---- epilogue: normalize + self-attn term, LDS repack, coalesced stores
#pragma unroll
  for (int mt = 0; mt < 4; ++mt)
#pragma unroll
    for (int r = 0; r < 4; ++r) {
      const int row = wr * 64 + mt * 16 + qd * 4 + r;   // local row, R = m0+row
      const float es  = eselfp[(size_t)b * 2048 + m0 + row];
      const float inv = 1.f / (es + Ls[(size_t)b * 2048 + m0 + row]);
      const short* mvr = mvbp + ((size_t)(b * 256 + row)) * 512;
#pragma unroll
      for (int j = 0; j < 4; ++j) {
        const int lcol = wc * 64 + j * 16 + ln;
        const float v = (acc[mt][j][r] + es * bf2f(mvr[n0 + lcol])) * inv;
        lds[row * 128 + (lcol ^ ((row & 7) << 3))] = f2bf(v);
      }
    }
  LGKM_WAIT();
  RAW_BAR();
#pragma unroll
  for (int it = 0; it < 8; ++it) {
    const int flat = it * 512 + t;
    const int row = flat >> 4, c = flat & 15;
    bf16x8 v = *(const bf16x8*)&lds[row * 128 + ((c ^ (row & 7)) * 8)];
    *(bf16x8*)(valb + ((size_t)(b * 256 + row)) * 4096 + (size_t)bz * 512 + n0 + c * 8) = v;
  }
}

// ---------------------------------------------------------------------------
// projq: merged {K/V projection (both streams), q projection} in ONE
// dispatch. Grid (8, 208): y<144 -> proj_kv path (big: y<128 input_seq,
// else memcells); y>=144 -> q-projection path (gemm128-MODE1 body):
// yy=y-144 in [0,64): z=yy&7, m0=((yy>>3)*2+(x>>2))*128, n0=(x&3)*128.
// All branches block-uniform. Both paths use 32 KiB LDS, (256,3), and the
// 1-barrier double-buffer schedule (r9/r10-verified).
// ---------------------------------------------------------------------------
__global__ __launch_bounds__(256, 3) void projq(
    const short* __restrict__ Ab, const short* __restrict__ Mb,
    const short* __restrict__ WkT, const short* __restrict__ WvT,
    const short* __restrict__ WqT,
    const float* __restrict__ bk, const float* __restrict__ bv,
    const float* __restrict__ bq,
    short* __restrict__ ikb, short* __restrict__ ivT,
    short* __restrict__ mkb, short* __restrict__ mvb,
    short* __restrict__ qb)
{
  __shared__ short Sh[16384];  // 32 KiB, layout differs per path
  const int t = threadIdx.x;
  const int w = t >> 6, lane = t & 63, qd = lane >> 4, ln = lane & 15;

  if (blockIdx.y >= 144) {
    // ================= q-projection path (gemm128 MODE1 body) ==============
    short* As = Sh;            // 2 x 4096
    short* Bs = Sh + 8192;     // 2 x 4096
    const int yy = blockIdx.y - 144;
    const int z  = yy & 7;
    const int m0 = ((yy >> 3) * 2 + (blockIdx.x >> 2)) * 128;
    const int n0 = (blockIdx.x & 3) * 128;
    const int wm = (w & 1) * 64, wn = (w >> 1) * 64;

    const short* A  = Mb;
    const short* Bp = WqT + (size_t)z * (512 * 512);

    const int rr = t >> 2, g0 = t & 3;
    const int gs0 = g0 ^ ((rr >> 1) & 3);
    const int gs1 = g0 ^ (((rr + 64) >> 1) & 3);
    const short* ga0 = A + (size_t)(m0 + rr) * 512 + gs0 * 8;
    const short* ga1 = A + (size_t)(m0 + rr + 64) * 512 + gs1 * 8;
    const short* gb0 = Bp + (size_t)(n0 + rr) * 512 + gs0 * 8;
    const short* gb1 = Bp + (size_t)(n0 + rr + 64) * 512 + gs1 * 8;

    int aoff[4], boff[4];
#pragma unroll
    for (int mt = 0; mt < 4; ++mt) {
      int r = wm + mt * 16 + ln;
      aoff[mt] = r * 32 + (qd ^ ((r >> 1) & 3)) * 8;
    }
#pragma unroll
    for (int nt = 0; nt < 4; ++nt) {
      int r = wn + nt * 16 + ln;
      boff[nt] = r * 32 + (qd ^ ((r >> 1) & 3)) * 8;
    }

    f32x4 acc[4][4];
#pragma unroll
    for (int mt = 0; mt < 4; ++mt)
#pragma unroll
      for (int nt = 0; nt < 4; ++nt) acc[mt][nt] = (f32x4){0.f, 0.f, 0.f, 0.f};

    gll16(ga0, &As[w * 512]);
    gll16(ga1, &As[2048 + w * 512]);
    gll16(gb0, &Bs[w * 512]);
    gll16(gb1, &Bs[2048 + w * 512]);
    asm volatile("s_waitcnt vmcnt(0)" ::: "memory");
    __builtin_amdgcn_s_barrier();

#pragma unroll 1
    for (int kc = 0; kc < 512; kc += 32) {
      const int p = (kc >> 5) & 1;
      short* Ap = &As[p * 4096];
      short* Bq = &Bs[p * 4096];

      bf16x8 af[4], bfr[4];
#pragma unroll
      for (int mt = 0; mt < 4; ++mt) af[mt] = *(const bf16x8*)&Ap[aoff[mt]];
#pragma unroll
      for (int nt = 0; nt < 4; ++nt) bfr[nt] = *(const bf16x8*)&Bq[boff[nt]];

      if (kc + 32 < 512) {
        const int nb = (p ^ 1) * 4096;
        gll16(ga0 + kc + 32, &As[nb + w * 512]);
        gll16(ga1 + kc + 32, &As[nb + 2048 + w * 512]);
        gll16(gb0 + kc + 32, &Bs[nb + w * 512]);
        gll16(gb1 + kc + 32, &Bs[nb + 2048 + w * 512]);
      }

      __builtin_amdgcn_s_setprio(1);
#pragma unroll
      for (int mt = 0; mt < 4; ++mt)
#pragma unroll
        for (int nt = 0; nt < 4; ++nt)
          acc[mt][nt] = __builtin_amdgcn_mfma_f32_16x16x32_bf16(af[mt], bfr[nt], acc[mt][nt], 0, 0, 0);
      __builtin_amdgcn_s_setprio(0);

      VMLG_WAIT();
      RAW_BAR();
    }

#pragma unroll
    for (int nt = 0; nt < 4; ++nt) {
      const int col = n0 + wn + nt * 16 + ln;
      const float bc = bq[512 * z + col];
#pragma unroll
      for (int mt = 0; mt < 4; ++mt)
#pragma unroll
        for (int r = 0; r < 4; ++r) {
          const int row = m0 + wm + mt * 16 + qd * 4 + r;
          const int bidx = row >> 8, ml = row & 255;
          qb[((size_t)(bidx * H_ + z) * M_ + ml) * 512 + col] = f2bf(acc[mt][nt][r] + bc);
        }
    }
    return;
  }

  // ================= K/V projection path =====================
  const bool big = blockIdx.y < 128;
  const int n0 = blockIdx.x * 64;
  const int m0 = (big ? blockIdx.y : (blockIdx.y - 128)) * 128;
  const int wm = (w & 1) * 64, wn2 = (w >> 1) * 32;

  const short* A = big ? Ab : Mb;
  short* Ck      = big ? ikb : mkb;

  const int rr = t >> 2, g0 = t & 3;
  const int gs0 = g0 ^ ((rr >> 1) & 3);
  const int gs1 = g0 ^ (((rr + 64) >> 1) & 3);
  const short* ga0 = A + (size_t)(m0 + rr) * 512 + gs0 * 8;
  const short* ga1 = A + (size_t)(m0 + rr + 64) * 512 + gs1 * 8;
  const short* gbk = WkT + (size_t)(n0 + rr) * 512 + gs0 * 8;
  const short* gbv = WvT + (size_t)(n0 + rr) * 512 + gs0 * 8;

  int aoff[4], boff[2];
#pragma unroll
  for (int mt = 0; mt < 4; ++mt) {
    int r = wm + mt * 16 + ln;
    aoff[mt] = r * 32 + (qd ^ ((r >> 1) & 3)) * 8;
  }
#pragma unroll
  for (int nt = 0; nt < 2; ++nt) {
    int r = wn2 + nt * 16 + ln;
    boff[nt] = r * 32 + (qd ^ ((r >> 1) & 3)) * 8;
  }

  f32x4 accK[4][2], accV[4][2];
#pragma unroll
  for (int mt = 0; mt < 4; ++mt)
#pragma unroll
    for (int nt = 0; nt < 2; ++nt) {
      accK[mt][nt] = (f32x4){0.f, 0.f, 0.f, 0.f};
      accV[mt][nt] = (f32x4){0.f, 0.f, 0.f, 0.f};
    }

  // prologue: stage tile0 -> buf0 (base = p*8192; A@0, Bk@4096, Bv@6144)
  gll16(ga0, &Sh[w * 512]);
  gll16(ga1, &Sh[2048 + w * 512]);
  gll16(gbk, &Sh[4096 + w * 512]);
  gll16(gbv, &Sh[6144 + w * 512]);
  asm volatile("s_waitcnt vmcnt(0)" ::: "memory");
  __builtin_amdgcn_s_barrier();

#pragma unroll 1
  for (int kc = 0; kc < 512; kc += 32) {
    const int base = ((kc >> 5) & 1) * 8192;

    bf16x8 af[4], bkf[2], bvf[2];
#pragma unroll
    for (int mt = 0; mt < 4; ++mt) af[mt] = *(const bf16x8*)&Sh[base + aoff[mt]];
#pragma unroll
    for (int nt = 0; nt < 2; ++nt) {
      bkf[nt] = *(const bf16x8*)&Sh[base + 4096 + boff[nt]];
      bvf[nt] = *(const bf16x8*)&Sh[base + 6144 + boff[nt]];
    }

    if (kc + 32 < 512) {
      const int nb = base ^ 8192;
      gll16(ga0 + kc + 32, &Sh[nb + w * 512]);
      gll16(ga1 + kc + 32, &Sh[nb + 2048 + w * 512]);
      gll16(gbk + kc + 32, &Sh[nb + 4096 + w * 512]);
      gll16(gbv + kc + 32, &Sh[nb + 6144 + w * 512]);
    }

    __builtin_amdgcn_s_setprio(1);
#pragma unroll
    for (int mt = 0; mt < 4; ++mt)
#pragma unroll
      for (int nt = 0; nt < 2; ++nt) {
        accK[mt][nt] = __builtin_amdgcn_mfma_f32_16x16x32_bf16(af[mt], bkf[nt], accK[mt][nt], 0, 0, 0);
        accV[mt][nt] = __builtin_amdgcn_mfma_f32_16x16x32_bf16(af[mt], bvf[nt], accV[mt][nt], 0, 0, 0);
      }
    __builtin_amdgcn_s_setprio(0);

    VMLG_WAIT();
    RAW_BAR();
  }

  // ---- K epilogue: direct scattered stores
#pragma unroll
  for (int nt = 0; nt < 2; ++nt) {
    const int col = n0 + wn2 + nt * 16 + ln;
    const float bc = bk[col];
#pragma unroll
    for (int mt = 0; mt < 4; ++mt)
#pragma unroll
      for (int r = 0; r < 4; ++r) {
        const int row = m0 + wm + mt * 16 + qd * 4 + r;
        Ck[(size_t)row * 512 + col] = f2bf(accK[mt][nt][r] + bc);
      }
  }

  // ---- V epilogue
  if (!big) {
#pragma unroll
    for (int nt = 0; nt < 2; ++nt) {
      const int col = n0 + wn2 + nt * 16 + ln;
      const float bc = bv[col];
#pragma unroll
      for (int mt = 0; mt < 4; ++mt)
#pragma unroll
        for (int r = 0; r < 4; ++r) {
          const int row = m0 + wm + mt * 16 + qd * 4 + r;
          mvb[(size_t)row * 512 + col] = f2bf(accV[mt][nt][r] + bc);
        }
    }
  } else {
    // transpose via LDS reuse (staging dead). per-wave 32x40 tile.
    __syncthreads();
    short* ep = &Sh[w * 1280];
    const int lr = lane >> 1, lc16 = (lane & 1) * 16;
#pragma unroll
    for (int pass = 0; pass < 2; ++pass) {
#pragma unroll
      for (int mh = 0; mh < 2; ++mh) {
        const int mt = pass * 2 + mh;
#pragma unroll
        for (int nt = 0; nt < 2; ++nt) {
          const float bc = bv[n0 + wn2 + nt * 16 + ln];
#pragma unroll
          for (int r = 0; r < 4; ++r)
            ep[(nt * 16 + ln) * 40 + mh * 16 + qd * 4 + r] = f2bf(accV[mt][nt][r] + bc);
        }
      }
      LGKM_WAIT();
      const int srow0 = m0 + wm + pass * 32;
      const int bidx = srow0 >> 11;
      const int sloc = (srow0 & 2047) + lc16;
      const int pcol = n0 + wn2 + lr;
      short* outp = ivT + (size_t)bidx * P_ * S_ + (size_t)pcol * S_ + sloc;
      *(bf16x8*)outp = *(const bf16x8*)&ep[lr * 40 + lc16];
      *(bf16x8*)(outp + 8) = *(const bf16x8*)&ep[lr * 40 + lc16 + 8];
      LGKM_WAIT();
    }
  }
}

// ---------------------------------------------------------------------------
// self-score + Ls zeroing
// ---------------------------------------------------------------------------
__global__ __launch_bounds__(256) void selfscore(
    const short* __restrict__ qb, const short* __restrict__ mkb,
    float* __restrict__ eself, float* __restrict__ Ls)
{
  const int z = blockIdx.x, t = threadIdx.x;
  const short* qr = qb + ((size_t)z * M_ + t) * P_;
  const short* mr = mkb + ((size_t)(z >> 3) * M_ + t) * P_;
  float s = 0.f;
#pragma unroll 8
  for (int c = 0; c < P_; c += 8) {
    bf16x8 qv = *(const bf16x8*)(qr + c);
    bf16x8 mv = *(const bf16x8*)(mr + c);
#pragma unroll
    for (int j = 0; j < 8; ++j) s += bf2f(qv[j]) * bf2f(mv[j]);
  }
  eself[(size_t)z * M_ + t] = __expf(s * SCALE);
  Ls[(size_t)z * M_ + t] = 0.f;
}

// ---------------------------------------------------------------------------
extern "C" void kernel_launch(void* const* d_in, const int* in_sizes, int n_in,
                              void* d_out, int out_size, void* d_ws, size_t ws_size,
                              hipStream_t stream) {
  const float* input_seq = (const float*)d_in[0];
  const float* memcells  = (const float*)d_in[1];
  const float* Wk = (const float*)d_in[2];
  const float* bk = (const float*)d_in[3];
  const float* Wv = (const float*)d_in[4];
  const float* bv = (const float*)d_in[5];
  const float* Wq = (const float*)d_in[6];
  const float* bq = (const float*)d_in[7];
  const float* Wo = (const float*)d_in[8];
  const float* bo = (const float*)d_in[9];
  float* out = (float*)d_out;

  short* ws = (short*)d_ws;
  size_t o = 0;
  short* valb = ws + o; o += (size_t)B_ * M_ * H_ * P_;      // 8388608
  short* WoT  = ws + o; o += (size_t)(H_ * P_) * P_;          // 2097152
  short* mvb  = ws + o; o += (size_t)B_ * M_ * P_;            // 1048576
  short* mkb  = ws + o; o += (size_t)B_ * M_ * P_;            // 1048576
  short* qb   = ws + o; o += (size_t)B_ * H_ * M_ * P_;       // 8388608
  short* ivT  = ws + o; o += (size_t)B_ * P_ * S_;            // 8388608
  short* ikb  = ws + o; o += (size_t)B_ * S_ * P_;            // 8388608
  float* eself = (float*)(ws + o); o += 2 * (size_t)B_ * H_ * M_;
  float* Ls    = (float*)(ws + o); o += 2 * (size_t)B_ * H_ * M_;
  short* region2 = ws + o;                                    // Eb region (64 MB)
  short* Ab  = region2;
  short* Mb  = Ab + (size_t)B_ * S_ * D_;
  short* WkT = Mb + (size_t)B_ * M_ * D_;
  short* WvT = WkT + (size_t)D_ * P_;
  short* WqT = WvT + (size_t)D_ * P_;
  short* Eb  = region2;   // overlaps the above (all dead before E is written)

  dim3 blk(256);

  // prep: casts + out-bias-init + all weight transposes in ONE dispatch
  const int n4A = B_ * S_ * D_ / 4;   // 2097152
  const int n4M = B_ * M_ * D_ / 4;   // 262144
  prep<<<dim3(14848), blk, 0, stream>>>(
      input_seq, Ab, n4A, memcells, Mb,
      Wk, Wv, Wq, WkT, WvT, WqT, Wo, WoT, bo, out);

  // merged K/V projections + q projection, one dispatch (8 x 208 blocks)
  projq<<<dim3(8, 208), blk, 0, stream>>>(
      Ab, Mb, WkT, WvT, WqT, bk, bv, bq, ikb, ivT, mkb, mvb, qb);

  // eself + zero Ls (before QK's atomics)
  selfscore<<<dim3(64), blk, 0, stream>>>(qb, mkb, eself, Ls);

  // E = exp(scale * q @ ik^T) + fused row-sum; per-batch 2048x2048, K=512
  qk256<8><<<dim3(8, 8, 8), dim3(512), 0, stream>>>(qb, ikb, Eb, Ls);

  // val = normalize(E @ iv + eself*mv), concat layout; per-batch 2048x512
  pv128<32><<<dim3(8, 4, 8), dim3(512), 0, stream>>>(Eb, ivT, valb, Ls, eself, mvb);

  // Wo: split-K=4, atomicAdd directly into out (bias pre-filled by prep)
  gemm128<5, 1024, 512, 4096, 4096><<<dim3(4, 16, 4), blk, 0, stream>>>(
      valb, WoT, nullptr, out, 1024, 1024, nullptr, nullptr, nullptr);
}

// Round 12
// 277.972 us; speedup vs baseline: 1.1722x; 1.0264x over previous
//
#include <hip/hip_runtime.h>

#define B_ 8
#define S_ 2048
#define M_ 256
#define D_ 512
#define P_ 512
#define H_ 8

#define SCALE 0.044194173824159216f  // 1/sqrt(512)

typedef __attribute__((ext_vector_type(8))) short bf16x8;
typedef __attribute__((ext_vector_type(4))) float f32x4;

static __device__ __forceinline__ float bf2f(short u) {
  union { float f; unsigned int i; } x;
  x.i = ((unsigned int)(unsigned short)u) << 16;
  return x.f;
}
static __device__ __forceinline__ short f2bf(float f) {
  union { float f; unsigned int i; } x;
  x.f = f;
  unsigned int r = (x.i + 0x7FFFu + ((x.i >> 16) & 1u)) >> 16;
  return (short)r;
}

// async global->LDS, 16B per lane; lds base must be wave-uniform
static __device__ __forceinline__ void gll16(const short* g, short* l) {
  __builtin_amdgcn_global_load_lds(
      (const __attribute__((address_space(1))) void*)g,
      (__attribute__((address_space(3))) void*)l, 16, 0, 0);
}

#define LGKM_WAIT() asm volatile("s_waitcnt lgkmcnt(0)" ::: "memory")
#define VMLG_WAIT() asm volatile("s_waitcnt vmcnt(0) lgkmcnt(0)" ::: "memory")
#define RAW_BAR() do { asm volatile("" ::: "memory"); __builtin_amdgcn_s_barrier(); asm volatile("" ::: "memory"); } while (0)

// ---------------------------------------------------------------------------
// prep: ONE dispatch replacing {cast_both, out-bias-init, Ls-zero,
// wtrans_all, wtrans_wo}. Flat block-id ranges; every branch block-uniform.
//   [0, 9216)        cast input_seq+memcells fp32 -> bf16
//   [9216, 10240)    out[i] = bo[i % 512]  (bias init for MODE5 atomics)
//   [10240, 10256)   Ls = 0 (16384 floats; moved here from selfscore so the
//                    eself blocks can ride inside the qk256 dispatch)
//   [10256, 12816)   wtrans_all
//   [12816, 14864)   wtrans_wo
// ---------------------------------------------------------------------------
__global__ __launch_bounds__(256) void prep(
    const float* __restrict__ inA, short* __restrict__ outA, int n4A,
    const float* __restrict__ inM, short* __restrict__ outM,
    const float* __restrict__ Wk, const float* __restrict__ Wv,
    const float* __restrict__ Wq,
    short* __restrict__ WkT, short* __restrict__ WvT, short* __restrict__ WqT,
    const float* __restrict__ Wo, short* __restrict__ WoT,
    const float* __restrict__ bo, float* __restrict__ out,
    float* __restrict__ Ls)
{
  __shared__ float tile[32][33];
  int bid = blockIdx.x;
  const int tthr = threadIdx.x;

  if (bid < 9216) {                       // ---- cast path
    int idx = bid * 256 + tthr;
    const float* in = inA;
    short* outp = outA;
    if (idx >= n4A) { idx -= n4A; in = inM; outp = outM; }
    float4 v = ((const float4*)in)[idx];
    short o0 = f2bf(v.x), o1 = f2bf(v.y), o2 = f2bf(v.z), o3 = f2bf(v.w);
    uint2 pk;
    pk.x = (unsigned int)(unsigned short)o0 | ((unsigned int)(unsigned short)o1 << 16);
    pk.y = (unsigned int)(unsigned short)o2 | ((unsigned int)(unsigned short)o3 << 16);
    ((uint2*)outp)[idx] = pk;
    return;
  }
  bid -= 9216;

  if (bid < 1024) {                       // ---- out = bias broadcast
    const int idx4 = bid * 256 + tthr;    // 262144 float4 = 2048x512 fp32
    ((float4*)out)[idx4] = ((const float4*)bo)[idx4 & 127];
    return;
  }
  bid -= 1024;

  if (bid < 16) {                         // ---- Ls = 0 (4096 float4)
    ((float4*)Ls)[bid * 256 + tthr] = (float4){0.f, 0.f, 0.f, 0.f};
    return;
  }
  bid -= 16;

  const int tx = tthr & 31, ty = tthr >> 5;

  if (bid < 2560) {                       // ---- wtrans_all
    const int z = bid >> 8, rem = bid & 255;
    const int n0 = (rem & 15) * 32, k0 = (rem >> 4) * 32;
    const float* inp;
    short* outp;
    if (z == 0)      { inp = Wk; outp = WkT; }
    else if (z == 1) { inp = Wv; outp = WvT; }
    else             { inp = Wq + (size_t)(z - 2) * 512 * 512;
                       outp = WqT + (size_t)(z - 2) * 512 * 512; }
#pragma unroll
    for (int i = 0; i < 4; ++i)
      tile[ty + 8 * i][tx] = inp[(size_t)(k0 + ty + 8 * i) * 512 + n0 + tx];
    __syncthreads();
#pragma unroll
    for (int i = 0; i < 4; ++i)
      outp[(size_t)(n0 + ty + 8 * i) * 512 + k0 + tx] = f2bf(tile[tx][ty + 8 * i]);
    return;
  }
  bid -= 2560;

  {                                       // ---- wtrans_wo (2048 blocks)
    const int n0 = (bid & 15) * 32, k0 = (bid >> 4) * 32;
#pragma unroll
    for (int i = 0; i < 4; ++i)
      tile[ty + 8 * i][tx] = Wo[(size_t)(k0 + ty + 8 * i) * 512 + n0 + tx];
    __syncthreads();
#pragma unroll
    for (int i = 0; i < 4; ++i)
      WoT[(size_t)(n0 + ty + 8 * i) * 4096 + k0 + tx] = f2bf(tile[tx][ty + 8 * i]);
  }
}

// ---------------------------------------------------------------------------
// 128x128 MFMA GEMM, BK=32, 1-barrier double-buffer loop. MODE 5 (Wo
// product): epilogue atomicAdds fp32 into out (bias pre-filled by prep).
// ---------------------------------------------------------------------------
template<int MODE, int K, int N, int LDA, int LDB>
__global__ __launch_bounds__(256, 3) void gemm128(
    const short* __restrict__ Abase, const short* __restrict__ Bbase,
    const float* __restrict__ bias, void* __restrict__ Cv,
    const size_t aZ, const size_t bZ,
    float* __restrict__ Ls,
    const float* __restrict__ eselfp, const short* __restrict__ mvbp)
{
  __shared__ short As[8192];   // 2 x 128x32
  __shared__ short Bs[8192];
  const int t = threadIdx.x;
  const int w = t >> 6, lane = t & 63, qd = lane >> 4, ln = lane & 15;
  const int wm = (w & 1) * 64, wn = (w >> 1) * 64;

  const int n0 = blockIdx.x * 128;
  const int m0 = blockIdx.y * 128;
  const int z = blockIdx.z;

  const short* A  = Abase + (size_t)z * aZ;
  const short* Bp = Bbase + (size_t)z * bZ;

  const int rr = t >> 2, g0 = t & 3;
  const int gs0 = g0 ^ ((rr >> 1) & 3);
  const int gs1 = g0 ^ (((rr + 64) >> 1) & 3);
  const short* ga0 = A + (size_t)(m0 + rr) * LDA + gs0 * 8;
  const short* ga1 = A + (size_t)(m0 + rr + 64) * LDA + gs1 * 8;
  const short* gb0 = Bp + (size_t)(n0 + rr) * LDB + gs0 * 8;
  const short* gb1 = Bp + (size_t)(n0 + rr + 64) * LDB + gs1 * 8;

  int aoff[4], boff[4];
#pragma unroll
  for (int mt = 0; mt < 4; ++mt) {
    int r = wm + mt * 16 + ln;
    aoff[mt] = r * 32 + (qd ^ ((r >> 1) & 3)) * 8;
  }
#pragma unroll
  for (int nt = 0; nt < 4; ++nt) {
    int r = wn + nt * 16 + ln;
    boff[nt] = r * 32 + (qd ^ ((r >> 1) & 3)) * 8;
  }

  f32x4 acc[4][4];
#pragma unroll
  for (int mt = 0; mt < 4; ++mt)
#pragma unroll
    for (int nt = 0; nt < 4; ++nt) acc[mt][nt] = (f32x4){0.f, 0.f, 0.f, 0.f};

  // prologue: stage tile0 -> buf0
  gll16(ga0, &As[w * 512]);
  gll16(ga1, &As[2048 + w * 512]);
  gll16(gb0, &Bs[w * 512]);
  gll16(gb1, &Bs[2048 + w * 512]);
  asm volatile("s_waitcnt vmcnt(0)" ::: "memory");
  __builtin_amdgcn_s_barrier();

#pragma unroll 1
  for (int kc = 0; kc < K; kc += 32) {
    const int p = (kc >> 5) & 1;
    short* Ap = &As[p * 4096];
    short* Bq = &Bs[p * 4096];

    bf16x8 af[4], bfr[4];
#pragma unroll
    for (int mt = 0; mt < 4; ++mt) af[mt] = *(const bf16x8*)&Ap[aoff[mt]];
#pragma unroll
    for (int nt = 0; nt < 4; ++nt) bfr[nt] = *(const bf16x8*)&Bq[boff[nt]];

    if (kc + 32 < K) {
      const int nb = (p ^ 1) * 4096;
      gll16(ga0 + kc + 32, &As[nb + w * 512]);
      gll16(ga1 + kc + 32, &As[nb + 2048 + w * 512]);
      gll16(gb0 + kc + 32, &Bs[nb + w * 512]);
      gll16(gb1 + kc + 32, &Bs[nb + 2048 + w * 512]);
    }

    __builtin_amdgcn_s_setprio(1);
#pragma unroll
    for (int mt = 0; mt < 4; ++mt)
#pragma unroll
      for (int nt = 0; nt < 4; ++nt)
        acc[mt][nt] = __builtin_amdgcn_mfma_f32_16x16x32_bf16(af[mt], bfr[nt], acc[mt][nt], 0, 0, 0);
    __builtin_amdgcn_s_setprio(0);

    VMLG_WAIT();
    RAW_BAR();
  }

  if constexpr (MODE == 5) {
#pragma unroll
    for (int nt = 0; nt < 4; ++nt) {
      const int col = n0 + wn + nt * 16 + ln;
#pragma unroll
      for (int mt = 0; mt < 4; ++mt)
#pragma unroll
        for (int r = 0; r < 4; ++r) {
          const int row = m0 + wm + mt * 16 + qd * 4 + r;
          atomicAdd(&((float*)Cv)[(size_t)row * N + col], acc[mt][nt][r]);
        }
    }
  } else {  // MODE 1 (unused in this round's launch; kept for completeness)
#pragma unroll
    for (int nt = 0; nt < 4; ++nt) {
      const int col = n0 + wn + nt * 16 + ln;
      const float bc = bias[512 * z + col];
#pragma unroll
      for (int mt = 0; mt < 4; ++mt)
#pragma unroll
        for (int r = 0; r < 4; ++r) {
          const int row = m0 + wm + mt * 16 + qd * 4 + r;
          const int bidx = row >> 8, ml = row & 255;
          ((short*)Cv)[((size_t)(bidx * H_ + z) * M_ + ml) * N + col] = f2bf(acc[mt][nt][r] + bc);
        }
    }
  }
}

// ---------------------------------------------------------------------------
// QK kernel + embedded selfscore: grid (8, 8, 9).
// z<8: r3/r11 structure: 256x256 tile, BK=64, 512 thr (8 waves 2Mx4N, wave
// 128x64), ONE barrier per K-tile; swizzle chunk c of row r at c^(r&7)
// staged via pre-swizzled global source (verified 0 conflicts).
// z==8: the 64 selfscore blocks (zz = y*8+x) computing eself = exp(scale *
// q[zz][m].mk[b][m]) on threads 0-255; runs concurrently with QK blocks,
// fully hidden under the GEMM. Ls-zeroing moved to prep so the atomics
// ordering constraint is preserved.
// ---------------------------------------------------------------------------
template<int NKT>
__global__ __launch_bounds__(512, 2) void qk256(
    const short* __restrict__ Abase, const short* __restrict__ Bbase,
    short* __restrict__ Eb, float* __restrict__ Ls,
    const short* __restrict__ mkb, float* __restrict__ eself)
{
  __shared__ short lds[65536];   // A: 2buf x [2half][128][64] | B same at +32768
  const int t = threadIdx.x;

  if (blockIdx.z == 8) {
    // ---- selfscore path (block-uniform; waves 4-7 idle)
    if (t < 256) {
      const int zz = blockIdx.y * 8 + blockIdx.x;     // 0..63 = b*8+h
      const short* qr = Abase + ((size_t)zz * M_ + t) * P_;
      const short* mr = mkb + ((size_t)(zz >> 3) * M_ + t) * P_;
      float s = 0.f;
#pragma unroll 8
      for (int c = 0; c < P_; c += 8) {
        bf16x8 qv = *(const bf16x8*)(qr + c);
        bf16x8 mv = *(const bf16x8*)(mr + c);
#pragma unroll
        for (int j = 0; j < 8; ++j) s += bf2f(qv[j]) * bf2f(mv[j]);
      }
      eself[(size_t)zz * M_ + t] = __expf(s * SCALE);
    }
    return;
  }

  const int w = t >> 6, lane = t & 63, qd = lane >> 4, ln = lane & 15;
  const int wr = w >> 2, wc = w & 3;
  const int b = blockIdx.x;                       // XCD pin: flat id % 8 == b
  const int n0 = blockIdx.y * 256, m0 = blockIdx.z * 256;

  const short* A  = Abase + (size_t)b * (2048 * 512) + (size_t)m0 * 512;
  const short* Bp = Bbase + (size_t)b * (2048 * 512) + (size_t)n0 * 512;

  const int s0 = w * 64 + lane, s1 = s0 + 512;
  const int sr0 = s0 >> 3, sc0 = ((s0 & 7) ^ (sr0 & 7)) * 8;
  const int sr1 = s1 >> 3, sc1 = ((s1 & 7) ^ (sr1 & 7)) * 8;
  auto stage = [&](const short* g, short* lbase) {
    gll16(g + (size_t)sr0 * 512 + sc0, lbase + w * 512);
    gll16(g + (size_t)sr1 * 512 + sc1, lbase + 4096 + w * 512);
  };

  const int cq0 = ((qd    ) ^ (ln & 7)) * 8;
  const int cq1 = ((4 + qd) ^ (ln & 7)) * 8;
  const int brow = (wc & 1) * 64;

  f32x4 acc[8][4];
#pragma unroll
  for (int i = 0; i < 8; ++i)
#pragma unroll
    for (int j = 0; j < 4; ++j) acc[i][j] = (f32x4){0.f, 0.f, 0.f, 0.f};

  // ---- prologue: stage tile0, drain, go
  stage(A,              &lds[0]);
  stage(A + 128 * 512,  &lds[8192]);
  stage(Bp,             &lds[32768]);
  stage(Bp + 128 * 512, &lds[32768 + 8192]);
  asm volatile("s_waitcnt vmcnt(0)" ::: "memory");
  __builtin_amdgcn_s_barrier();

#pragma unroll 1
  for (int kt = 0; kt < NKT; ++kt) {
    const int p = kt & 1;
    short* Ah = &lds[p * 16384 + wr * 8192];
    short* Bh = &lds[32768 + p * 16384 + (wc >> 1) * 8192];

    bf16x8 a0[8], b0[4];
#pragma unroll
    for (int j = 0; j < 4; ++j)
      b0[j] = *(const bf16x8*)&Bh[(brow + j * 16 + ln) * 64 + cq0];
#pragma unroll
    for (int mt = 0; mt < 8; ++mt)
      a0[mt] = *(const bf16x8*)&Ah[(mt * 16 + ln) * 64 + cq0];
    if (kt + 1 < NKT) {
      stage(A  + (size_t)(kt + 1) * 64,             &lds[(p ^ 1) * 16384]);
      stage(A  + 128 * 512 + (size_t)(kt + 1) * 64, &lds[(p ^ 1) * 16384 + 8192]);
      stage(Bp + (size_t)(kt + 1) * 64,             &lds[32768 + (p ^ 1) * 16384]);
      stage(Bp + 128 * 512 + (size_t)(kt + 1) * 64, &lds[32768 + (p ^ 1) * 16384 + 8192]);
    }
    __builtin_amdgcn_s_setprio(1);
#pragma unroll
    for (int mt = 0; mt < 8; ++mt)
#pragma unroll
      for (int j = 0; j < 4; ++j)
        acc[mt][j] = __builtin_amdgcn_mfma_f32_16x16x32_bf16(a0[mt], b0[j], acc[mt][j], 0, 0, 0);
    __builtin_amdgcn_s_setprio(0);

    bf16x8 a1[8], b1[4];
#pragma unroll
    for (int j = 0; j < 4; ++j)
      b1[j] = *(const bf16x8*)&Bh[(brow + j * 16 + ln) * 64 + cq1];
#pragma unroll
    for (int mt = 0; mt < 8; ++mt)
      a1[mt] = *(const bf16x8*)&Ah[(mt * 16 + ln) * 64 + cq1];
    __builtin_amdgcn_s_setprio(1);
#pragma unroll
    for (int mt = 0; mt < 8; ++mt)
#pragma unroll
      for (int j = 0; j < 4; ++j)
        acc[mt][j] = __builtin_amdgcn_mfma_f32_16x16x32_bf16(a1[mt], b1[j], acc[mt][j], 0, 0, 0);
    __builtin_amdgcn_s_setprio(0);

    VMLG_WAIT();
    RAW_BAR();
  }

  // ---- epilogue: exp, rowsum atomics, LDS repack, coalesced stores
#pragma unroll
  for (int i = 0; i < 8; ++i)
#pragma unroll
    for (int j = 0; j < 4; ++j)
#pragma unroll
      for (int r = 0; r < 4; ++r)
        acc[i][j][r] = __expf(acc[i][j][r] * SCALE);
#pragma unroll
  for (int i = 0; i < 8; ++i)
#pragma unroll
    for (int r = 0; r < 4; ++r) {
      float rs = acc[i][0][r] + acc[i][1][r] + acc[i][2][r] + acc[i][3][r];
      rs += __shfl_xor(rs, 1);
      rs += __shfl_xor(rs, 2);
      rs += __shfl_xor(rs, 4);
      rs += __shfl_xor(rs, 8);
      if (ln == 0) {
        const int row = m0 + wr * 128 + i * 16 + qd * 4 + r;
        atomicAdd(&Ls[(size_t)b * 2048 + row], rs);
      }
    }
#pragma unroll
  for (int i = 0; i < 8; ++i)
#pragma unroll
    for (int j = 0; j < 4; ++j)
#pragma unroll
      for (int r = 0; r < 4; ++r) {
        const int row = wr * 128 + i * 16 + qd * 4 + r;
        const int col = wc * 64 + j * 16 + ln;
        lds[row * 256 + (col ^ ((row & 7) << 3))] = f2bf(acc[i][j][r]);
      }
  LGKM_WAIT();
  RAW_BAR();
  short* Cb = Eb + (size_t)b * 2048 * 2048;
#pragma unroll
  for (int it = 0; it < 16; ++it) {
    const int flat = it * 512 + t;
    const int row = flat >> 5, c = flat & 31;
    bf16x8 v = *(const bf16x8*)&lds[row * 256 + ((c ^ (row & 7)) * 8)];
    *(bf16x8*)(Cb + (size_t)(m0 + row) * 2048 + n0 + c * 8) = v;
  }
}

// ---------------------------------------------------------------------------
// PV kernel (r4/r11 structure): 256x128 tile, BK=64, NKT=32, 512 thr,
// wave grid 4Mx2N (wave 64x64). RING-3 LDS (144 KiB), counted boundary
// vmcnt(6). One barrier/tile.
// ---------------------------------------------------------------------------
template<int NKT>
__global__ __launch_bounds__(512, 2) void pv128(
    const short* __restrict__ Abase, const short* __restrict__ Bbase,
    short* __restrict__ valb, const float* __restrict__ Ls,
    const float* __restrict__ eselfp, const short* __restrict__ mvbp)
{
  __shared__ short lds[73728];   // A ring 3x16384 @0, B ring 3x8192 @49152
  const int t = threadIdx.x;
  const int w = t >> 6, lane = t & 63, qd = lane >> 4, ln = lane & 15;
  const int wr = w >> 1, wc = w & 1;              // 4M x 2N
  const int b = blockIdx.x;                       // XCD pin
  const int n0 = blockIdx.y * 128;
  const int bz = blockIdx.z;                      // head tile: m0 = bz*256
  const int m0 = bz * 256;

  const short* A  = Abase + (size_t)b * (2048 * 2048) + (size_t)m0 * 2048;
  const short* Bp = Bbase + (size_t)b * (512 * 2048) + (size_t)n0 * 2048;

  const int s0 = w * 64 + lane, s1 = s0 + 512;
  const int sr0 = s0 >> 3, sc0 = ((s0 & 7) ^ (sr0 & 7)) * 8;
  const int sr1 = s1 >> 3, sc1 = ((s1 & 7) ^ (sr1 & 7)) * 8;
  auto stage = [&](const short* g, short* lbase) {   // 8192 shorts (128 rows)
    gll16(g + (size_t)sr0 * 2048 + sc0, lbase + w * 512);
    gll16(g + (size_t)sr1 * 2048 + sc1, lbase + 4096 + w * 512);
  };

  const int cq0 = ((qd    ) ^ (ln & 7)) * 8;
  const int cq1 = ((4 + qd) ^ (ln & 7)) * 8;

  short* Ar = &lds[0];     short* An = &lds[16384]; short* Aw = &lds[32768];
  short* Br = &lds[49152]; short* Bn = &lds[57344]; short* Bw = &lds[65536];

  f32x4 acc[4][4];
#pragma unroll
  for (int i = 0; i < 4; ++i)
#pragma unroll
    for (int j = 0; j < 4; ++j) acc[i][j] = (f32x4){0.f, 0.f, 0.f, 0.f};

  // ---- prologue: tile0 -> buf0, tile1 -> buf1; wait tile0 only
  stage(A,                   Ar);
  stage(A + 128 * 2048,      Ar + 8192);
  stage(Bp,                  Br);
  stage(A + 64,              An);
  stage(A + 128 * 2048 + 64, An + 8192);
  stage(Bp + 64,             Bn);
  asm volatile("s_waitcnt vmcnt(6)" ::: "memory");
  __builtin_amdgcn_s_barrier();

#pragma unroll 1
  for (int kt = 0; kt < NKT; ++kt) {
    short* Ah = Ar + (wr >> 1) * 8192 + (wr & 1) * 4096;   // wave's 64-row window
    short* Bh = Br;

    bf16x8 a0[4], b0[4];
#pragma unroll
    for (int j = 0; j < 4; ++j)
      b0[j] = *(const bf16x8*)&Bh[(wc * 64 + j * 16 + ln) * 64 + cq0];
#pragma unroll
    for (int mt = 0; mt < 4; ++mt)
      a0[mt] = *(const bf16x8*)&Ah[(mt * 16 + ln) * 64 + cq0];

    if (kt + 2 < NKT) {
      stage(A  + (size_t)(kt + 2) * 64,              Aw);
      stage(A  + 128 * 2048 + (size_t)(kt + 2) * 64, Aw + 8192);
      stage(Bp + (size_t)(kt + 2) * 64,              Bw);
    }

    __builtin_amdgcn_s_setprio(1);
#pragma unroll
    for (int mt = 0; mt < 4; ++mt)
#pragma unroll
      for (int j = 0; j < 4; ++j)
        acc[mt][j] = __builtin_amdgcn_mfma_f32_16x16x32_bf16(a0[mt], b0[j], acc[mt][j], 0, 0, 0);
    __builtin_amdgcn_s_setprio(0);

    bf16x8 a1[4], b1[4];
#pragma unroll
    for (int j = 0; j < 4; ++j)
      b1[j] = *(const bf16x8*)&Bh[(wc * 64 + j * 16 + ln) * 64 + cq1];
#pragma unroll
    for (int mt = 0; mt < 4; ++mt)
      a1[mt] = *(const bf16x8*)&Ah[(mt * 16 + ln) * 64 + cq1];
    __builtin_amdgcn_s_setprio(1);
#pragma unroll
    for (int mt = 0; mt < 4; ++mt)
#pragma unroll
      for (int j = 0; j < 4; ++j)
        acc[mt][j] = __builtin_amdgcn_mfma_f32_16x16x32_bf16(a1[mt], b1[j], acc[mt][j], 0, 0, 0);
    __builtin_amdgcn_s_setprio(0);

    if (kt + 2 < NKT) { asm volatile("s_waitcnt vmcnt(6) lgkmcnt(0)" ::: "memory"); }
    else              { asm volatile("s_waitcnt vmcnt(0) lgkmcnt(0)" ::: "memory"); }
    RAW_BAR();

    short* tA = Ar; Ar = An; An = Aw; Aw = tA;
    short* tB = Br; Br = Bn; Bn = Bw; Bw = tB;
  }

  // ---- epilogue: normalize + self-attn term, LDS repack, coalesced stores
#pragma unroll
  for (int mt = 0; mt < 4; ++mt)
#pragma unroll
    for (int r = 0; r < 4; ++r) {
      const int row = wr * 64 + mt * 16 + qd * 4 + r;   // local row, R = m0+row
      const float es  = eselfp[(size_t)b * 2048 + m0 + row];
      const float inv = 1.f / (es + Ls[(size_t)b * 2048 + m0 + row]);
      const short* mvr = mvbp + ((size_t)(b * 256 + row)) * 512;
#pragma unroll
      for (int j = 0; j < 4; ++j) {
        const int lcol = wc * 64 + j * 16 + ln;
        const float v = (acc[mt][j][r] + es * bf2f(mvr[n0 + lcol])) * inv;
        lds[row * 128 + (lcol ^ ((row & 7) << 3))] = f2bf(v);
      }
    }
  LGKM_WAIT();
  RAW_BAR();
#pragma unroll
  for (int it = 0; it < 8; ++it) {
    const int flat = it * 512 + t;
    const int row = flat >> 4, c = flat & 15;
    bf16x8 v = *(const bf16x8*)&lds[row * 128 + ((c ^ (row & 7)) * 8)];
    *(bf16x8*)(valb + ((size_t)(b * 256 + row)) * 4096 + (size_t)bz * 512 + n0 + c * 8) = v;
  }
}

// ---------------------------------------------------------------------------
// projq: merged {K/V projection (both streams), q projection} in ONE
// dispatch. Grid (8, 208): y<144 -> proj_kv path (big: y<128 input_seq,
// else memcells); y>=144 -> q-projection path:
// yy=y-144 in [0,64): z=yy&7, m0=((yy>>3)*2+(x>>2))*128, n0=(x&3)*128.
// All branches block-uniform. Both paths use 32 KiB LDS, (256,3), and the
// 1-barrier double-buffer schedule.
// ---------------------------------------------------------------------------
__global__ __launch_bounds__(256, 3) void projq(
    const short* __restrict__ Ab, const short* __restrict__ Mb,
    const short* __restrict__ WkT, const short* __restrict__ WvT,
    const short* __restrict__ WqT,
    const float* __restrict__ bk, const float* __restrict__ bv,
    const float* __restrict__ bq,
    short* __restrict__ ikb, short* __restrict__ ivT,
    short* __restrict__ mkb, short* __restrict__ mvb,
    short* __restrict__ qb)
{
  __shared__ short Sh[16384];  // 32 KiB, layout differs per path
  const int t = threadIdx.x;
  const int w = t >> 6, lane = t & 63, qd = lane >> 4, ln = lane & 15;

  if (blockIdx.y >= 144) {
    // ================= q-projection path ==============
    short* As = Sh;            // 2 x 4096
    short* Bs = Sh + 8192;     // 2 x 4096
    const int yy = blockIdx.y - 144;
    const int z  = yy & 7;
    const int m0 = ((yy >> 3) * 2 + (blockIdx.x >> 2)) * 128;
    const int n0 = (blockIdx.x & 3) * 128;
    const int wm = (w & 1) * 64, wn = (w >> 1) * 64;

    const short* A  = Mb;
    const short* Bp = WqT + (size_t)z * (512 * 512);

    const int rr = t >> 2, g0 = t & 3;
    const int gs0 = g0 ^ ((rr >> 1) & 3);
    const int gs1 = g0 ^ (((rr + 64) >> 1) & 3);
    const short* ga0 = A + (size_t)(m0 + rr) * 512 + gs0 * 8;
    const short* ga1 = A + (size_t)(m0 + rr + 64) * 512 + gs1 * 8;
    const short* gb0 = Bp + (size_t)(n0 + rr) * 512 + gs0 * 8;
    const short* gb1 = Bp + (size_t)(n0 + rr + 64) * 512 + gs1 * 8;

    int aoff[4], boff[4];
#pragma unroll
    for (int mt = 0; mt < 4; ++mt) {
      int r = wm + mt * 16 + ln;
      aoff[mt] = r * 32 + (qd ^ ((r >> 1) & 3)) * 8;
    }
#pragma unroll
    for (int nt = 0; nt < 4; ++nt) {
      int r = wn + nt * 16 + ln;
      boff[nt] = r * 32 + (qd ^ ((r >> 1) & 3)) * 8;
    }

    f32x4 acc[4][4];
#pragma unroll
    for (int mt = 0; mt < 4; ++mt)
#pragma unroll
      for (int nt = 0; nt < 4; ++nt) acc[mt][nt] = (f32x4){0.f, 0.f, 0.f, 0.f};

    gll16(ga0, &As[w * 512]);
    gll16(ga1, &As[2048 + w * 512]);
    gll16(gb0, &Bs[w * 512]);
    gll16(gb1, &Bs[2048 + w * 512]);
    asm volatile("s_waitcnt vmcnt(0)" ::: "memory");
    __builtin_amdgcn_s_barrier();

#pragma unroll 1
    for (int kc = 0; kc < 512; kc += 32) {
      const int p = (kc >> 5) & 1;
      short* Ap = &As[p * 4096];
      short* Bq = &Bs[p * 4096];

      bf16x8 af[4], bfr[4];
#pragma unroll
      for (int mt = 0; mt < 4; ++mt) af[mt] = *(const bf16x8*)&Ap[aoff[mt]];
#pragma unroll
      for (int nt = 0; nt < 4; ++nt) bfr[nt] = *(const bf16x8*)&Bq[boff[nt]];

      if (kc + 32 < 512) {
        const int nb = (p ^ 1) * 4096;
        gll16(ga0 + kc + 32, &As[nb + w * 512]);
        gll16(ga1 + kc + 32, &As[nb + 2048 + w * 512]);
        gll16(gb0 + kc + 32, &Bs[nb + w * 512]);
        gll16(gb1 + kc + 32, &Bs[nb + 2048 + w * 512]);
      }

      __builtin_amdgcn_s_setprio(1);
#pragma unroll
      for (int mt = 0; mt < 4; ++mt)
#pragma unroll
        for (int nt = 0; nt < 4; ++nt)
          acc[mt][nt] = __builtin_amdgcn_mfma_f32_16x16x32_bf16(af[mt], bfr[nt], acc[mt][nt], 0, 0, 0);
      __builtin_amdgcn_s_setprio(0);

      VMLG_WAIT();
      RAW_BAR();
    }

#pragma unroll
    for (int nt = 0; nt < 4; ++nt) {
      const int col = n0 + wn + nt * 16 + ln;
      const float bc = bq[512 * z + col];
#pragma unroll
      for (int mt = 0; mt < 4; ++mt)
#pragma unroll
        for (int r = 0; r < 4; ++r) {
          const int row = m0 + wm + mt * 16 + qd * 4 + r;
          const int bidx = row >> 8, ml = row & 255;
          qb[((size_t)(bidx * H_ + z) * M_ + ml) * 512 + col] = f2bf(acc[mt][nt][r] + bc);
        }
    }
    return;
  }

  // ================= K/V projection path =====================
  const bool big = blockIdx.y < 128;
  const int n0 = blockIdx.x * 64;
  const int m0 = (big ? blockIdx.y : (blockIdx.y - 128)) * 128;
  const int wm = (w & 1) * 64, wn2 = (w >> 1) * 32;

  const short* A = big ? Ab : Mb;
  short* Ck      = big ? ikb : mkb;

  const int rr = t >> 2, g0 = t & 3;
  const int gs0 = g0 ^ ((rr >> 1) & 3);
  const int gs1 = g0 ^ (((rr + 64) >> 1) & 3);
  const short* ga0 = A + (size_t)(m0 + rr) * 512 + gs0 * 8;
  const short* ga1 = A + (size_t)(m0 + rr + 64) * 512 + gs1 * 8;
  const short* gbk = WkT + (size_t)(n0 + rr) * 512 + gs0 * 8;
  const short* gbv = WvT + (size_t)(n0 + rr) * 512 + gs0 * 8;

  int aoff[4], boff[2];
#pragma unroll
  for (int mt = 0; mt < 4; ++mt) {
    int r = wm + mt * 16 + ln;
    aoff[mt] = r * 32 + (qd ^ ((r >> 1) & 3)) * 8;
  }
#pragma unroll
  for (int nt = 0; nt < 2; ++nt) {
    int r = wn2 + nt * 16 + ln;
    boff[nt] = r * 32 + (qd ^ ((r >> 1) & 3)) * 8;
  }

  f32x4 accK[4][2], accV[4][2];
#pragma unroll
  for (int mt = 0; mt < 4; ++mt)
#pragma unroll
    for (int nt = 0; nt < 2; ++nt) {
      accK[mt][nt] = (f32x4){0.f, 0.f, 0.f, 0.f};
      accV[mt][nt] = (f32x4){0.f, 0.f, 0.f, 0.f};
    }

  // prologue: stage tile0 -> buf0 (base = p*8192; A@0, Bk@4096, Bv@6144)
  gll16(ga0, &Sh[w * 512]);
  gll16(ga1, &Sh[2048 + w * 512]);
  gll16(gbk, &Sh[4096 + w * 512]);
  gll16(gbv, &Sh[6144 + w * 512]);
  asm volatile("s_waitcnt vmcnt(0)" ::: "memory");
  __builtin_amdgcn_s_barrier();

#pragma unroll 1
  for (int kc = 0; kc < 512; kc += 32) {
    const int base = ((kc >> 5) & 1) * 8192;

    bf16x8 af[4], bkf[2], bvf[2];
#pragma unroll
    for (int mt = 0; mt < 4; ++mt) af[mt] = *(const bf16x8*)&Sh[base + aoff[mt]];
#pragma unroll
    for (int nt = 0; nt < 2; ++nt) {
      bkf[nt] = *(const bf16x8*)&Sh[base + 4096 + boff[nt]];
      bvf[nt] = *(const bf16x8*)&Sh[base + 6144 + boff[nt]];
    }

    if (kc + 32 < 512) {
      const int nb = base ^ 8192;
      gll16(ga0 + kc + 32, &Sh[nb + w * 512]);
      gll16(ga1 + kc + 32, &Sh[nb + 2048 + w * 512]);
      gll16(gbk + kc + 32, &Sh[nb + 4096 + w * 512]);
      gll16(gbv + kc + 32, &Sh[nb + 6144 + w * 512]);
    }

    __builtin_amdgcn_s_setprio(1);
#pragma unroll
    for (int mt = 0; mt < 4; ++mt)
#pragma unroll
      for (int nt = 0; nt < 2; ++nt) {
        accK[mt][nt] = __builtin_amdgcn_mfma_f32_16x16x32_bf16(af[mt], bkf[nt], accK[mt][nt], 0, 0, 0);
        accV[mt][nt] = __builtin_amdgcn_mfma_f32_16x16x32_bf16(af[mt], bvf[nt], accV[mt][nt], 0, 0, 0);
      }
    __builtin_amdgcn_s_setprio(0);

    VMLG_WAIT();
    RAW_BAR();
  }

  // ---- K epilogue: direct scattered stores
#pragma unroll
  for (int nt = 0; nt < 2; ++nt) {
    const int col = n0 + wn2 + nt * 16 + ln;
    const float bc = bk[col];
#pragma unroll
    for (int mt = 0; mt < 4; ++mt)
#pragma unroll
      for (int r = 0; r < 4; ++r) {
        const int row = m0 + wm + mt * 16 + qd * 4 + r;
        Ck[(size_t)row * 512 + col] = f2bf(accK[mt][nt][r] + bc);
      }
  }

  // ---- V epilogue
  if (!big) {
#pragma unroll
    for (int nt = 0; nt < 2; ++nt) {
      const int col = n0 + wn2 + nt * 16 + ln;
      const float bc = bv[col];
#pragma unroll
      for (int mt = 0; mt < 4; ++mt)
#pragma unroll
        for (int r = 0; r < 4; ++r) {
          const int row = m0 + wm + mt * 16 + qd * 4 + r;
          mvb[(size_t)row * 512 + col] = f2bf(accV[mt][nt][r] + bc);
        }
    }
  } else {
    // transpose via LDS reuse (staging dead). per-wave 32x40 tile.
    __syncthreads();
    short* ep = &Sh[w * 1280];
    const int lr = lane >> 1, lc16 = (lane & 1) * 16;
#pragma unroll
    for (int pass = 0; pass < 2; ++pass) {
#pragma unroll
      for (int mh = 0; mh < 2; ++mh) {
        const int mt = pass * 2 + mh;
#pragma unroll
        for (int nt = 0; nt < 2; ++nt) {
          const float bc = bv[n0 + wn2 + nt * 16 + ln];
#pragma unroll
          for (int r = 0; r < 4; ++r)
            ep[(nt * 16 + ln) * 40 + mh * 16 + qd * 4 + r] = f2bf(accV[mt][nt][r] + bc);
        }
      }
      LGKM_WAIT();
      const int srow0 = m0 + wm + pass * 32;
      const int bidx = srow0 >> 11;
      const int sloc = (srow0 & 2047) + lc16;
      const int pcol = n0 + wn2 + lr;
      short* outp = ivT + (size_t)bidx * P_ * S_ + (size_t)pcol * S_ + sloc;
      *(bf16x8*)outp = *(const bf16x8*)&ep[lr * 40 + lc16];
      *(bf16x8*)(outp + 8) = *(const bf16x8*)&ep[lr * 40 + lc16 + 8];
      LGKM_WAIT();
    }
  }
}

// ---------------------------------------------------------------------------
extern "C" void kernel_launch(void* const* d_in, const int* in_sizes, int n_in,
                              void* d_out, int out_size, void* d_ws, size_t ws_size,
                              hipStream_t stream) {
  const float* input_seq = (const float*)d_in[0];
  const float* memcells  = (const float*)d_in[1];
  const float* Wk = (const float*)d_in[2];
  const float* bk = (const float*)d_in[3];
  const float* Wv = (const float*)d_in[4];
  const float* bv = (const float*)d_in[5];
  const float* Wq = (const float*)d_in[6];
  const float* bq = (const float*)d_in[7];
  const float* Wo = (const float*)d_in[8];
  const float* bo = (const float*)d_in[9];
  float* out = (float*)d_out;

  short* ws = (short*)d_ws;
  size_t o = 0;
  short* valb = ws + o; o += (size_t)B_ * M_ * H_ * P_;      // 8388608
  short* WoT  = ws + o; o += (size_t)(H_ * P_) * P_;          // 2097152
  short* mvb  = ws + o; o += (size_t)B_ * M_ * P_;            // 1048576
  short* mkb  = ws + o; o += (size_t)B_ * M_ * P_;            // 1048576
  short* qb   = ws + o; o += (size_t)B_ * H_ * M_ * P_;       // 8388608
  short* ivT  = ws + o; o += (size_t)B_ * P_ * S_;            // 8388608
  short* ikb  = ws + o; o += (size_t)B_ * S_ * P_;            // 8388608
  float* eself = (float*)(ws + o); o += 2 * (size_t)B_ * H_ * M_;
  float* Ls    = (float*)(ws + o); o += 2 * (size_t)B_ * H_ * M_;
  short* region2 = ws + o;                                    // Eb region (64 MB)
  short* Ab  = region2;
  short* Mb  = Ab + (size_t)B_ * S_ * D_;
  short* WkT = Mb + (size_t)B_ * M_ * D_;
  short* WvT = WkT + (size_t)D_ * P_;
  short* WqT = WvT + (size_t)D_ * P_;
  short* Eb  = region2;   // overlaps the above (all dead before E is written)

  dim3 blk(256);

  // prep: casts + out-bias-init + Ls-zero + weight transposes, ONE dispatch
  const int n4A = B_ * S_ * D_ / 4;   // 2097152
  const int n4M = B_ * M_ * D_ / 4;   // 262144
  prep<<<dim3(14864), blk, 0, stream>>>(
      input_seq, Ab, n4A, memcells, Mb,
      Wk, Wv, Wq, WkT, WvT, WqT, Wo, WoT, bo, out, Ls);

  // merged K/V projections + q projection, one dispatch (8 x 208 blocks)
  projq<<<dim3(8, 208), blk, 0, stream>>>(
      Ab, Mb, WkT, WvT, WqT, bk, bv, bq, ikb, ivT, mkb, mvb, qb);

  // E = exp(scale * q @ ik^T) + fused row-sum; z==8 plane = embedded
  // selfscore blocks (eself), hidden under the GEMM
  qk256<8><<<dim3(8, 8, 9), dim3(512), 0, stream>>>(qb, ikb, Eb, Ls, mkb, eself);

  // val = normalize(E @ iv + eself*mv), concat layout; per-batch 2048x512
  pv128<32><<<dim3(8, 4, 8), dim3(512), 0, stream>>>(Eb, ivT, valb, Ls, eself, mvb);

  // Wo: split-K=4, atomicAdd directly into out (bias pre-filled by prep)
  gemm128<5, 1024, 512, 4096, 4096><<<dim3(4, 16, 4), blk, 0, stream>>>(
      valb, WoT, nullptr, out, 1024, 1024, nullptr, nullptr, nullptr);
}